// Round 14
// baseline (383.880 us; speedup 1.0000x reference)
//
#include <hip/hip_runtime.h>
#include <math.h>

#define IN_F 128
#define F1 256   // H1*C1
#define H1 2
#define F2 64
#define NEG 0.2f

typedef _Float16 f16x8 __attribute__((ext_vector_type(8)));
typedef _Float16 f16x4 __attribute__((ext_vector_type(4)));
typedef float f32x4 __attribute__((ext_vector_type(4)));

// ---------------- tiled fp32 GEMM (round-9 best) — used for layer 2 ----------
template<int KTOT, int TM, int TN, int RM, int RN, int LDA, int LDW, int LDC,
         bool RELU, bool ATT_EP, bool HEADOFF>
__global__ __launch_bounds__(256) void gemm_tiled(
    const float* __restrict__ A, const float* __restrict__ bias,
    const float* __restrict__ W, float* __restrict__ C,
    const float* __restrict__ att_s, const float* __restrict__ att_d,
    float* __restrict__ a_src, float* __restrict__ a_dst, int M)
{
    constexpr int NX = TN / RN;
    constexpr int NY = 256 / NX;
    static_assert(NY * RM == TM, "tile mismatch");
    static_assert(RN == 8, "split-col mapping assumes RN==8");
    __shared__ float As[32][TM];
    __shared__ float Ws[32][TN];
    int t = threadIdx.x;
    int tx = t % NX, ty = t / NX;
    int m0 = blockIdx.x * TM;
    int n0 = blockIdx.y * TN;
    long aoff = HEADOFF ? (long)blockIdx.y * KTOT : 0;
    float acc[RM][RN];
    #pragma unroll
    for (int i = 0; i < RM; ++i)
        #pragma unroll
        for (int j = 0; j < RN; ++j) acc[i][j] = 0.f;

    constexpr int PARTS = 256 / TM;
    constexpr int F4PT = 8 / PARTS;
    int ar = t % TM, apart = t / TM;
    int arow = m0 + ar; if (arow >= M) arow = M - 1;
    constexpr int WTPK = TN / 4;
    constexpr int WKP = 256 / WTPK;
    int wk0 = t / WTPK, wc = t % WTPK;

    for (int kc = 0; kc < KTOT; kc += 32) {
        const float* ap = A + (long)arow * LDA + aoff + kc + apart * (F4PT * 4);
        #pragma unroll
        for (int p = 0; p < F4PT; ++p) {
            int kk = apart * (F4PT * 4) + p * 4;
            float4 v = *(const float4*)(ap + p * 4);
            if (RELU) {
                float4 bb = *(const float4*)&bias[kc + kk];
                v.x = fmaxf(v.x + bb.x, 0.f);
                v.y = fmaxf(v.y + bb.y, 0.f);
                v.z = fmaxf(v.z + bb.z, 0.f);
                v.w = fmaxf(v.w + bb.w, 0.f);
            }
            As[kk + 0][ar] = v.x;
            As[kk + 1][ar] = v.y;
            As[kk + 2][ar] = v.z;
            As[kk + 3][ar] = v.w;
        }
        #pragma unroll
        for (int p = 0; p < 32 / WKP; ++p) {
            int k = wk0 + p * WKP;
            *(float4*)&Ws[k][wc * 4] =
                *(const float4*)&W[(long)(kc + k) * LDW + n0 + wc * 4];
        }
        __syncthreads();
        #pragma unroll 4
        for (int k = 0; k < 32; ++k) {
            float av[RM], wv[RN];
            #pragma unroll
            for (int i4 = 0; i4 < RM / 4; ++i4) {
                float4 v = *(const float4*)&As[k][ty * RM + i4 * 4];
                av[i4 * 4 + 0] = v.x; av[i4 * 4 + 1] = v.y;
                av[i4 * 4 + 2] = v.z; av[i4 * 4 + 3] = v.w;
            }
            {
                float4 v = *(const float4*)&Ws[k][tx * 4];
                wv[0] = v.x; wv[1] = v.y; wv[2] = v.z; wv[3] = v.w;
                float4 u = *(const float4*)&Ws[k][TN / 2 + tx * 4];
                wv[4] = u.x; wv[5] = u.y; wv[6] = u.z; wv[7] = u.w;
            }
            #pragma unroll
            for (int i = 0; i < RM; ++i)
                #pragma unroll
                for (int j = 0; j < RN; ++j)
                    acc[i][j] = fmaf(av[i], wv[j], acc[i][j]);
        }
        __syncthreads();
    }
    #pragma unroll
    for (int i = 0; i < RM; ++i) {
        int row = m0 + ty * RM + i;
        if (row < M) {
            float4 o0 = {acc[i][0], acc[i][1], acc[i][2], acc[i][3]};
            float4 o1 = {acc[i][4], acc[i][5], acc[i][6], acc[i][7]};
            *(float4*)&C[(long)row * LDC + n0 + tx * 4] = o0;
            *(float4*)&C[(long)row * LDC + n0 + TN / 2 + tx * 4] = o1;
        }
    }
    if (ATT_EP) {
        float asr[RN], adr[RN];
        #pragma unroll
        for (int j = 0; j < RN; ++j) {
            int col = (j < 4) ? (tx * 4 + j) : (TN / 2 + tx * 4 + j - 4);
            asr[j] = att_s[col];
            adr[j] = att_d[col];
        }
        #pragma unroll
        for (int i = 0; i < RM; ++i) {
            float ps = 0.f, pd = 0.f;
            #pragma unroll
            for (int j = 0; j < RN; ++j) {
                ps = fmaf(acc[i][j], asr[j], ps);
                pd = fmaf(acc[i][j], adr[j], pd);
            }
            #pragma unroll
            for (int o = 1; o < NX; o <<= 1) {
                ps += __shfl_xor(ps, o);
                pd += __shfl_xor(pd, o);
            }
            int row = m0 + ty * RM + i;
            if (tx == 0 && row < M) { a_src[row] = ps; a_dst[row] = pd; }
        }
    }
}

// ------- layer-1 GEMM via split-f16 MFMA: z1 = (Gh+Gl) @ (Wh+Wl) -------------
// C = Ah*Bh + Al*Bh + Ah*Bl (Al*Bl ~2^-22, dropped). Error ~1e-6 rel: fp32-class.
// Layouts (m89/m91/m120-verified): A[m=lane&15][k=quad*8+j]; B[k][n=lane&15]
// with same k mapping (Wt stored transposed [n][k] for contiguous loads);
// C: col=lane&15, row=quad*4+reg.
__global__ __launch_bounds__(256) void gemm1_mfma(
    const _Float16* __restrict__ Gh, const _Float16* __restrict__ Gl,
    const _Float16* __restrict__ Wth, const _Float16* __restrict__ Wtl,
    float* __restrict__ z1, int N)
{
    int wave = threadIdx.x >> 6, lane = threadIdx.x & 63;
    int ct = blockIdx.x;                 // 16 col-tiles of 16
    int quad = lane >> 4, l4 = lane & 15;
    int col = ct * 16 + l4;
    f16x8 bh[4], bl[4];
    {
        const _Float16* wb  = Wth + (long)col * IN_F + quad * 8;
        const _Float16* wbl = Wtl + (long)col * IN_F + quad * 8;
        #pragma unroll
        for (int ks = 0; ks < 4; ++ks) {
            bh[ks] = *(const f16x8*)(wb + ks * 32);
            bl[ks] = *(const f16x8*)(wbl + ks * 32);
        }
    }
    long ahead = (long)(ct >> 3) * 128;  // head offset into G's 256 cols
    int rt0 = (blockIdx.y * 4 + wave) * 8;
    for (int i8 = 0; i8 < 8; ++i8) {
        int rt = rt0 + i8;
        if (rt * 16 >= N) return;
        long m = (long)rt * 16 + l4;
        const _Float16* ap  = Gh + m * F1 + ahead + quad * 8;
        const _Float16* alp = Gl + m * F1 + ahead + quad * 8;
        f32x4 acc = {0.f, 0.f, 0.f, 0.f};
        #pragma unroll
        for (int ks = 0; ks < 4; ++ks) {
            f16x8 ah = *(const f16x8*)(ap + ks * 32);
            f16x8 al = *(const f16x8*)(alp + ks * 32);
            acc = __builtin_amdgcn_mfma_f32_16x16x32_f16(ah, bh[ks], acc, 0, 0, 0);
            acc = __builtin_amdgcn_mfma_f32_16x16x32_f16(al, bh[ks], acc, 0, 0, 0);
            acc = __builtin_amdgcn_mfma_f32_16x16x32_f16(ah, bl[ks], acc, 0, 0, 0);
        }
        int rbase = rt * 16 + quad * 4;
        #pragma unroll
        for (int i = 0; i < 4; ++i)
            z1[(long)(rbase + i) * F1 + col] = acc[i];
    }
}

// ------- launch 1: histogram + UV precompute + W1 transpose/split ------------
__global__ __launch_bounds__(256) void hist_uv_k(
    const int* __restrict__ ei_d, int* __restrict__ deg, int* __restrict__ pos,
    int E, int Ep, int NBH,
    const float* __restrict__ W1, const float* __restrict__ as1,
    const float* __restrict__ ad1, float* __restrict__ UV4,
    _Float16* __restrict__ Wth, _Float16* __restrict__ Wtl)
{
    if ((int)blockIdx.x < NBH) {
        int i = blockIdx.x * 256 + threadIdx.x;
        if (i >= Ep) return;
        int d = (i < E) ? ei_d[i] : (i - E);
        pos[i] = atomicAdd(&deg[d], 1);
    } else if ((int)blockIdx.x == NBH) {
        int t = threadIdx.x;
        int k = t >> 1, h = t & 1;
        const float* wrow = W1 + (long)k * F1 + h * 128;
        const float* sa = as1 + h * 128;
        const float* da = ad1 + h * 128;
        float u = 0.f, v = 0.f;
        for (int c = 0; c < 128; ++c) {
            float w = wrow[c];
            u = fmaf(w, sa[c], u);
            v = fmaf(w, da[c], v);
        }
        UV4[k * 4 + h] = u;
        UV4[k * 4 + 2 + h] = v;
    } else {
        // W1t[n][k] split into f16 hi/lo
        int n = threadIdx.x;
        for (int k = 0; k < IN_F; ++k) {
            float w = W1[(long)k * F1 + n];
            _Float16 hh = (_Float16)w;
            Wth[(long)n * IN_F + k] = hh;
            Wtl[(long)n * IN_F + k] = (_Float16)(w - (float)hh);
        }
    }
}

// ------- launch 2: per-block local scan -> rloc + att1v ----------------------
__global__ __launch_bounds__(1024) void scanA_att_k(
    const int* __restrict__ deg, int* __restrict__ rloc, int* __restrict__ bsum,
    int N, int NBLK,
    const float* __restrict__ x, const float* __restrict__ UV4,
    float* __restrict__ a_src, float* __restrict__ a_dst)
{
    if ((int)blockIdx.x < NBLK) {
        __shared__ int wsum[16];
        int t = threadIdx.x, lane = t & 63, w = t >> 6;
        int i = blockIdx.x * 1024 + t;
        int v = (i < N) ? deg[i] : 0;
        int incl = v;
        #pragma unroll
        for (int o = 1; o < 64; o <<= 1) {
            int nb = __shfl_up(incl, o);
            if (lane >= o) incl += nb;
        }
        if (lane == 63) wsum[w] = incl;
        __syncthreads();
        if (w == 0 && lane < 16) {
            int s = wsum[lane];
            #pragma unroll
            for (int o = 1; o < 16; o <<= 1) {
                int nb = __shfl_up(s, o);
                if (lane >= o) s += nb;
            }
            wsum[lane] = s;
        }
        __syncthreads();
        int woff = (w == 0) ? 0 : wsum[w - 1];
        if (i < N) rloc[i] = woff + incl - v;
        if (t == 1023) bsum[blockIdx.x] = woff + incl;
    } else {
        int wave = threadIdx.x >> 6, lane = threadIdx.x & 63;
        int n = ((int)blockIdx.x - NBLK) * 16 + wave;
        if (n >= N) return;
        float2 xv = ((const float2*)(x + (long)n * IN_F))[lane];
        float4 u0 = ((const float4*)UV4)[2 * lane];
        float4 u1 = ((const float4*)UV4)[2 * lane + 1];
        float p0 = xv.x * u0.x + xv.y * u1.x;
        float p1 = xv.x * u0.y + xv.y * u1.y;
        float p2 = xv.x * u0.z + xv.y * u1.z;
        float p3 = xv.x * u0.w + xv.y * u1.w;
        #pragma unroll
        for (int o = 32; o > 0; o >>= 1) {
            p0 += __shfl_xor(p0, o); p1 += __shfl_xor(p1, o);
            p2 += __shfl_xor(p2, o); p3 += __shfl_xor(p3, o);
        }
        if (lane == 0) {
            a_src[(long)n * 2 + 0] = p0; a_src[(long)n * 2 + 1] = p1;
            a_dst[(long)n * 2 + 0] = p2; a_dst[(long)n * 2 + 1] = p3;
        }
    }
}

// ------- launch 3 (fused): rowptr fixup + atomic-free scatter ----------------
__global__ __launch_bounds__(1024) void scat_fix_k(
    const int* __restrict__ ei_s, const int* __restrict__ ei_d,
    const int* __restrict__ rloc, const int* __restrict__ bsum,
    const int* __restrict__ pos, int* __restrict__ rowptr,
    int* __restrict__ csr_src, int* __restrict__ csr_eid,
    int E, int Ep, int N, int NBLK)
{
    __shared__ int bexs[64];
    __shared__ int tot_sh;
    int t = threadIdx.x;
    if (t < 64) {
        int v = (t < NBLK) ? bsum[t] : 0;
        int incl = v;
        #pragma unroll
        for (int o = 1; o < 64; o <<= 1) {
            int nb = __shfl_up(incl, o);
            if (t >= o) incl += nb;
        }
        bexs[t] = incl - v;
        if (t == NBLK - 1) tot_sh = incl;
    }
    __syncthreads();
    if ((int)blockIdx.x < NBLK) {
        int i = blockIdx.x * 1024 + t;
        if (i < N) rowptr[i] = rloc[i] + bexs[blockIdx.x];
        if ((int)blockIdx.x == NBLK - 1 && t == 0) rowptr[N] = tot_sh;
    } else {
        int i = ((int)blockIdx.x - NBLK) * 1024 + t;
        if (i >= Ep) return;
        int s = (i < E) ? ei_s[i] : (i - E);
        int d = (i < E) ? ei_d[i] : (i - E);
        int at = rloc[d] + bexs[d >> 10] + pos[i];
        csr_src[at] = s;
        csr_eid[at] = (i < E) ? i : -1;
    }
}

// ------- layer-1 aggregation in INPUT space; emits split-f16 G ---------------
__global__ __launch_bounds__(256) void agg1x(
    const int* __restrict__ rowptr, const int* __restrict__ csr_src,
    const float* __restrict__ a_s, const float* __restrict__ a_d,  // [N,2]
    const float* __restrict__ x, _Float16* __restrict__ Gh,
    _Float16* __restrict__ Gl, int N)
{
    int wave = threadIdx.x >> 6, lane = threadIdx.x & 63;
    int d = blockIdx.x * 4 + wave;
    if (d >= N) return;
    int row = rowptr[d], end = rowptr[d + 1];
    int h = lane >> 5, l5 = lane & 31;
    float adh = a_d[(long)d * 2 + h];
    float a0[4] = {0,0,0,0}, a1[4] = {0,0,0,0};
    float den = 0.f;
    for (int base = row; base < end; base += 32) {
        int cnt = min(32, end - base);
        int sreg = 0; float e = 0.f;
        if (l5 < cnt) {
            sreg = csr_src[base + l5];
            float v = a_s[(long)sreg * 2 + h] + adh;
            v = (v > 0.f) ? v : NEG * v;
            e = expf(v);
            den += e;
        }
        int jmax = (cnt + 1) >> 1;
        for (int j = 0; j < jmax; ++j) {
            int m = 2 * j + h;
            int s = __shfl(sreg, m);
            float w0 = __shfl(e, m);
            float w1 = __shfl(e, 32 | m);
            float4 v = *(const float4*)(x + (long)s * IN_F + l5 * 4);
            a0[0] = fmaf(w0, v.x, a0[0]); a0[1] = fmaf(w0, v.y, a0[1]);
            a0[2] = fmaf(w0, v.z, a0[2]); a0[3] = fmaf(w0, v.w, a0[3]);
            a1[0] = fmaf(w1, v.x, a1[0]); a1[1] = fmaf(w1, v.y, a1[1]);
            a1[2] = fmaf(w1, v.z, a1[2]); a1[3] = fmaf(w1, v.w, a1[3]);
        }
    }
    #pragma unroll
    for (int o = 16; o > 0; o >>= 1) den += __shfl_xor(den, o);
    #pragma unroll
    for (int p = 0; p < 4; ++p) {
        a0[p] += __shfl_xor(a0[p], 32);
        a1[p] += __shfl_xor(a1[p], 32);
    }
    float inv = 1.0f / (den + 1e-16f);
    float* acch = (h == 0) ? a0 : a1;
    f16x4 hi, lo;
    #pragma unroll
    for (int p = 0; p < 4; ++p) {
        float v = acch[p] * inv;
        hi[p] = (_Float16)v;
        lo[p] = (_Float16)(v - (float)hi[p]);
    }
    long base = (long)d * F1 + h * 128 + l5 * 4;
    *(f16x4*)(Gh + base) = hi;
    *(f16x4*)(Gl + base) = lo;
}

// ------- layer-2 aggregation (bias fused into output) ------------------------
__global__ __launch_bounds__(256) void agg2_csr(
    const int* __restrict__ rowptr, const int* __restrict__ csr_src,
    const float* __restrict__ a_s, const float* __restrict__ a_d,  // [N]
    const float* __restrict__ xh2, const float* __restrict__ b2,
    float* __restrict__ out2b, int N)
{
    int wave = threadIdx.x >> 6, lane = threadIdx.x & 63;
    int d = blockIdx.x * 4 + wave;
    if (d >= N) return;
    int row = rowptr[d], end = rowptr[d + 1];
    float adv = a_d[d];
    int g = lane >> 4, q = lane & 15;
    float acc[4] = {0,0,0,0};
    float den = 0.f;
    for (int base = row; base < end; base += 64) {
        int cnt = min(64, end - base);
        float ev = 0.f; int sreg = 0;
        if (lane < cnt) {
            sreg = csr_src[base + lane];
            float v = a_s[sreg] + adv; v = (v > 0.f) ? v : NEG * v;
            ev = expf(v);
            den += ev;
        }
        int jmax = (cnt + 3) >> 2;
        for (int j = 0; j < jmax; ++j) {
            int m = 4 * j + g;
            int s = __shfl(sreg, m);
            float w = __shfl(ev, m);
            float4 v = *(const float4*)(xh2 + (long)s * F2 + q * 4);
            acc[0] = fmaf(w, v.x, acc[0]); acc[1] = fmaf(w, v.y, acc[1]);
            acc[2] = fmaf(w, v.z, acc[2]); acc[3] = fmaf(w, v.w, acc[3]);
        }
    }
    #pragma unroll
    for (int o = 32; o > 0; o >>= 1) den += __shfl_xor(den, o);
    #pragma unroll
    for (int p = 0; p < 4; ++p) {
        acc[p] += __shfl_xor(acc[p], 16);
        acc[p] += __shfl_xor(acc[p], 32);
    }
    if (g == 0) {
        float inv = 1.0f / (den + 1e-16f);
        float4 bb = *(const float4*)&b2[q * 4];
        float4 o4 = {acc[0] * inv + bb.x, acc[1] * inv + bb.y,
                     acc[2] * inv + bb.z, acc[3] * inv + bb.w};
        *(float4*)(out2b + (long)d * F2 + q * 4) = o4;
    }
}

// ------- decode via CSR ------------------------------------------------------
__global__ __launch_bounds__(256) void decode_csr(
    const int* __restrict__ rowptr, const int* __restrict__ csr_src,
    const int* __restrict__ csr_eid, const float* __restrict__ z2b,
    float* __restrict__ out, int N)
{
    int wave = threadIdx.x >> 6, lane = threadIdx.x & 63;
    int d = blockIdx.x * 4 + wave;
    if (d >= N) return;
    int row = rowptr[d], end = rowptr[d + 1];
    int g = lane >> 4, q = lane & 15;
    float4 vd = *(const float4*)(z2b + (long)d * F2 + q * 4);
    for (int base = row; base < end; base += 64) {
        int cnt = min(64, end - base);
        int sreg = 0, ereg = -1;
        if (lane < cnt) {
            sreg = csr_src[base + lane];
            ereg = csr_eid[base + lane];
        }
        int jmax = (cnt + 3) >> 2;
        for (int j = 0; j < jmax; ++j) {
            int m = 4 * j + g;
            int s = __shfl(sreg, m);
            int eid = __shfl(ereg, m);
            float4 vs = *(const float4*)(z2b + (long)s * F2 + q * 4);
            float p = vd.x * vs.x + vd.y * vs.y + vd.z * vs.z + vd.w * vs.w;
            #pragma unroll
            for (int o = 1; o < 16; o <<= 1) p += __shfl_xor(p, o);
            if (q == 0 && eid >= 0) out[eid] = p;
        }
    }
}

extern "C" void kernel_launch(void* const* d_in, const int* in_sizes, int n_in,
                              void* d_out, int out_size, void* d_ws, size_t ws_size,
                              hipStream_t stream) {
    const float* x   = (const float*)d_in[0];
    const int*   ei  = (const int*)d_in[1];
    const float* W1  = (const float*)d_in[2];
    const float* as1 = (const float*)d_in[3];
    const float* ad1 = (const float*)d_in[4];
    const float* b1  = (const float*)d_in[5];
    const float* W2  = (const float*)d_in[6];
    const float* as2 = (const float*)d_in[7];
    const float* ad2 = (const float*)d_in[8];
    const float* b2  = (const float*)d_in[9];

    int N  = in_sizes[0] / IN_F;   // 50000
    int E  = in_sizes[1] / 2;      // 600000
    int Ep = E + N;
    const int* ei_src = ei;
    const int* ei_dst = ei + E;

    float* ws = (float*)d_ws;
    size_t off = 0;
    auto alloc = [&](size_t n) { float* p = ws + off; off += (n + 63) & ~(size_t)63; return p; };

    _Float16* Gh  = (_Float16*)alloc((size_t)N * F1 / 2);
    _Float16* Gl  = (_Float16*)alloc((size_t)N * F1 / 2);
    _Float16* Wth = (_Float16*)alloc(IN_F * F1 / 2);
    _Float16* Wtl = (_Float16*)alloc(IN_F * F1 / 2);
    float* z1     = alloc((size_t)N * F1);
    float* xh2    = alloc((size_t)N * F2);
    float* out2b  = alloc((size_t)N * F2);
    float* a_src1 = alloc((size_t)N * H1);
    float* a_dst1 = alloc((size_t)N * H1);
    float* a_src2 = alloc(N);
    float* a_dst2 = alloc(N);
    float* UV4    = alloc(IN_F * 4);
    int* rowptr   = (int*)alloc(N + 64);
    int* rloc     = (int*)alloc(N + 64);
    int* csr_src  = (int*)alloc(Ep);
    int* csr_eid  = (int*)alloc(Ep);
    int* pos      = (int*)alloc(Ep);
    int* bsum     = (int*)alloc(64);
    int* deg      = (int*)alloc(N);
    hipMemsetAsync(deg, 0, (size_t)N * sizeof(int), stream);

    int NBLK = (N + 1023) / 1024;       // 49
    int NBH  = (Ep + 255) / 256;
    int NBS  = (Ep + 1023) / 1024;
    int NBA  = (N + 15) / 16;

    hist_uv_k<<<NBH + 2, 256, 0, stream>>>(ei_dst, deg, pos, E, Ep, NBH,
                                           W1, as1, ad1, UV4, Wth, Wtl);
    scanA_att_k<<<NBLK + NBA, 1024, 0, stream>>>(deg, rloc, bsum, N, NBLK,
                                                 x, UV4, a_src1, a_dst1);
    scat_fix_k<<<NBLK + NBS, 1024, 0, stream>>>(ei_src, ei_dst, rloc, bsum, pos,
                                                rowptr, csr_src, csr_eid,
                                                E, Ep, N, NBLK);

    // layer 1: aggregate x into split-f16 G, then MFMA GEMM
    agg1x<<<(N + 3) / 4, 256, 0, stream>>>(rowptr, csr_src, a_src1, a_dst1, x,
                                           Gh, Gl, N);
    int NRT = (N + 15) / 16;            // 3125 row-tiles
    int NBY = (NRT + 31) / 32;          // 4 waves x 8 tiles per block
    gemm1_mfma<<<dim3(16, NBY), 256, 0, stream>>>(Gh, Gl, Wth, Wtl, z1, N);

    // layer 2 (vector GEMM, relu+bias staged, att epilogue)
    int mt1 = (N + 127) / 128;
    gemm_tiled<F1, 128, 64, 4, 8, F1, F2, F2, true, true, false>
        <<<dim3(mt1, 1), 256, 0, stream>>>(
        z1, b1, W2, xh2, as2, ad2, a_src2, a_dst2, N);
    agg2_csr<<<(N + 3) / 4, 256, 0, stream>>>(rowptr, csr_src, a_src2, a_dst2, xh2, b2, out2b, N);

    // decode via CSR
    decode_csr<<<(N + 3) / 4, 256, 0, stream>>>(rowptr, csr_src, csr_eid, out2b,
                                                (float*)d_out, N);
}

// Round 15
// 375.867 us; speedup vs baseline: 1.0213x; 1.0213x over previous
//
#include <hip/hip_runtime.h>
#include <math.h>

#define IN_F 128
#define F1 256   // H1*C1
#define H1 2
#define F2 64
#define NEG 0.2f

typedef _Float16 f16x8 __attribute__((ext_vector_type(8)));
typedef _Float16 f16x4 __attribute__((ext_vector_type(4)));
typedef float f32x4 __attribute__((ext_vector_type(4)));

// ---------------- tiled fp32 GEMM (round-9 best) — used for layer 2 ----------
template<int KTOT, int TM, int TN, int RM, int RN, int LDA, int LDW, int LDC,
         bool RELU, bool ATT_EP, bool HEADOFF>
__global__ __launch_bounds__(256) void gemm_tiled(
    const float* __restrict__ A, const float* __restrict__ bias,
    const float* __restrict__ W, float* __restrict__ C,
    const float* __restrict__ att_s, const float* __restrict__ att_d,
    float* __restrict__ a_src, float* __restrict__ a_dst, int M)
{
    constexpr int NX = TN / RN;
    constexpr int NY = 256 / NX;
    static_assert(NY * RM == TM, "tile mismatch");
    static_assert(RN == 8, "split-col mapping assumes RN==8");
    __shared__ float As[32][TM];
    __shared__ float Ws[32][TN];
    int t = threadIdx.x;
    int tx = t % NX, ty = t / NX;
    int m0 = blockIdx.x * TM;
    int n0 = blockIdx.y * TN;
    long aoff = HEADOFF ? (long)blockIdx.y * KTOT : 0;
    float acc[RM][RN];
    #pragma unroll
    for (int i = 0; i < RM; ++i)
        #pragma unroll
        for (int j = 0; j < RN; ++j) acc[i][j] = 0.f;

    constexpr int PARTS = 256 / TM;
    constexpr int F4PT = 8 / PARTS;
    int ar = t % TM, apart = t / TM;
    int arow = m0 + ar; if (arow >= M) arow = M - 1;
    constexpr int WTPK = TN / 4;
    constexpr int WKP = 256 / WTPK;
    int wk0 = t / WTPK, wc = t % WTPK;

    for (int kc = 0; kc < KTOT; kc += 32) {
        const float* ap = A + (long)arow * LDA + aoff + kc + apart * (F4PT * 4);
        #pragma unroll
        for (int p = 0; p < F4PT; ++p) {
            int kk = apart * (F4PT * 4) + p * 4;
            float4 v = *(const float4*)(ap + p * 4);
            if (RELU) {
                float4 bb = *(const float4*)&bias[kc + kk];
                v.x = fmaxf(v.x + bb.x, 0.f);
                v.y = fmaxf(v.y + bb.y, 0.f);
                v.z = fmaxf(v.z + bb.z, 0.f);
                v.w = fmaxf(v.w + bb.w, 0.f);
            }
            As[kk + 0][ar] = v.x;
            As[kk + 1][ar] = v.y;
            As[kk + 2][ar] = v.z;
            As[kk + 3][ar] = v.w;
        }
        #pragma unroll
        for (int p = 0; p < 32 / WKP; ++p) {
            int k = wk0 + p * WKP;
            *(float4*)&Ws[k][wc * 4] =
                *(const float4*)&W[(long)(kc + k) * LDW + n0 + wc * 4];
        }
        __syncthreads();
        #pragma unroll 4
        for (int k = 0; k < 32; ++k) {
            float av[RM], wv[RN];
            #pragma unroll
            for (int i4 = 0; i4 < RM / 4; ++i4) {
                float4 v = *(const float4*)&As[k][ty * RM + i4 * 4];
                av[i4 * 4 + 0] = v.x; av[i4 * 4 + 1] = v.y;
                av[i4 * 4 + 2] = v.z; av[i4 * 4 + 3] = v.w;
            }
            {
                float4 v = *(const float4*)&Ws[k][tx * 4];
                wv[0] = v.x; wv[1] = v.y; wv[2] = v.z; wv[3] = v.w;
                float4 u = *(const float4*)&Ws[k][TN / 2 + tx * 4];
                wv[4] = u.x; wv[5] = u.y; wv[6] = u.z; wv[7] = u.w;
            }
            #pragma unroll
            for (int i = 0; i < RM; ++i)
                #pragma unroll
                for (int j = 0; j < RN; ++j)
                    acc[i][j] = fmaf(av[i], wv[j], acc[i][j]);
        }
        __syncthreads();
    }
    #pragma unroll
    for (int i = 0; i < RM; ++i) {
        int row = m0 + ty * RM + i;
        if (row < M) {
            float4 o0 = {acc[i][0], acc[i][1], acc[i][2], acc[i][3]};
            float4 o1 = {acc[i][4], acc[i][5], acc[i][6], acc[i][7]};
            *(float4*)&C[(long)row * LDC + n0 + tx * 4] = o0;
            *(float4*)&C[(long)row * LDC + n0 + TN / 2 + tx * 4] = o1;
        }
    }
    if (ATT_EP) {
        float asr[RN], adr[RN];
        #pragma unroll
        for (int j = 0; j < RN; ++j) {
            int col = (j < 4) ? (tx * 4 + j) : (TN / 2 + tx * 4 + j - 4);
            asr[j] = att_s[col];
            adr[j] = att_d[col];
        }
        #pragma unroll
        for (int i = 0; i < RM; ++i) {
            float ps = 0.f, pd = 0.f;
            #pragma unroll
            for (int j = 0; j < RN; ++j) {
                ps = fmaf(acc[i][j], asr[j], ps);
                pd = fmaf(acc[i][j], adr[j], pd);
            }
            #pragma unroll
            for (int o = 1; o < NX; o <<= 1) {
                ps += __shfl_xor(ps, o);
                pd += __shfl_xor(pd, o);
            }
            int row = m0 + ty * RM + i;
            if (tx == 0 && row < M) { a_src[row] = ps; a_dst[row] = pd; }
        }
    }
}

// ------- layer-1 GEMM via split-f16 MFMA, row-resident blocking --------------
// Each block owns 64 rows (wave=16) and computes ALL 256 cols: G read exactly
// once (round 14's col-tile grid refetched G 8x across XCDs -> 200MB FETCH).
// A-frags for both heads live in registers; B-frags stream from L2 (W=128KB).
// C = Ah*Bh + Al*Bh + Ah*Bl (Al*Bl ~2^-22 dropped): fp32-class accuracy
// (verified round 14: absmax identical to fp32 path).
__global__ __launch_bounds__(256) void gemm1_mfma(
    const _Float16* __restrict__ Gh, const _Float16* __restrict__ Gl,
    const _Float16* __restrict__ Wth, const _Float16* __restrict__ Wtl,
    float* __restrict__ z1, int N)
{
    int wave = threadIdx.x >> 6, lane = threadIdx.x & 63;
    int quad = lane >> 4, l4 = lane & 15;
    int w0 = blockIdx.x * 64 + wave * 16;
    if (w0 >= N) return;
    int mrow = w0 + l4; if (mrow >= N) mrow = N - 1;

    f16x8 ah[2][4], al[2][4];
    const _Float16* gh = Gh + (long)mrow * F1 + quad * 8;
    const _Float16* gl = Gl + (long)mrow * F1 + quad * 8;
    #pragma unroll
    for (int h = 0; h < 2; ++h)
        #pragma unroll
        for (int ks = 0; ks < 4; ++ks) {
            ah[h][ks] = *(const f16x8*)(gh + h * 128 + ks * 32);
            al[h][ks] = *(const f16x8*)(gl + h * 128 + ks * 32);
        }
    int rbase = w0 + quad * 4;
    for (int ct = 0; ct < 16; ++ct) {
        int h = ct >> 3;
        int col = ct * 16 + l4;
        const _Float16* wb = Wth + (long)col * IN_F + quad * 8;
        const _Float16* wl = Wtl + (long)col * IN_F + quad * 8;
        f32x4 acc = {0.f, 0.f, 0.f, 0.f};
        #pragma unroll
        for (int ks = 0; ks < 4; ++ks) {
            f16x8 bh = *(const f16x8*)(wb + ks * 32);
            f16x8 bl = *(const f16x8*)(wl + ks * 32);
            acc = __builtin_amdgcn_mfma_f32_16x16x32_f16(ah[h][ks], bh, acc, 0, 0, 0);
            acc = __builtin_amdgcn_mfma_f32_16x16x32_f16(al[h][ks], bh, acc, 0, 0, 0);
            acc = __builtin_amdgcn_mfma_f32_16x16x32_f16(ah[h][ks], bl, acc, 0, 0, 0);
        }
        #pragma unroll
        for (int i = 0; i < 4; ++i) {
            int row = rbase + i;
            if (row < N) z1[(long)row * F1 + ct * 16 + l4] = acc[i];
        }
    }
}

// ------- launch 1: histogram + UV precompute + W1 transpose/split ------------
__global__ __launch_bounds__(256) void hist_uv_k(
    const int* __restrict__ ei_d, int* __restrict__ deg, int* __restrict__ pos,
    int E, int Ep, int NBH,
    const float* __restrict__ W1, const float* __restrict__ as1,
    const float* __restrict__ ad1, float* __restrict__ UV4,
    _Float16* __restrict__ Wth, _Float16* __restrict__ Wtl)
{
    if ((int)blockIdx.x < NBH) {
        int i = blockIdx.x * 256 + threadIdx.x;
        if (i >= Ep) return;
        int d = (i < E) ? ei_d[i] : (i - E);
        pos[i] = atomicAdd(&deg[d], 1);
    } else if ((int)blockIdx.x == NBH) {
        int t = threadIdx.x;
        int k = t >> 1, h = t & 1;
        const float* wrow = W1 + (long)k * F1 + h * 128;
        const float* sa = as1 + h * 128;
        const float* da = ad1 + h * 128;
        float u = 0.f, v = 0.f;
        for (int c = 0; c < 128; ++c) {
            float w = wrow[c];
            u = fmaf(w, sa[c], u);
            v = fmaf(w, da[c], v);
        }
        UV4[k * 4 + h] = u;
        UV4[k * 4 + 2 + h] = v;
    } else {
        // W1t[n][k] split into f16 hi/lo
        int n = threadIdx.x;
        for (int k = 0; k < IN_F; ++k) {
            float w = W1[(long)k * F1 + n];
            _Float16 hh = (_Float16)w;
            Wth[(long)n * IN_F + k] = hh;
            Wtl[(long)n * IN_F + k] = (_Float16)(w - (float)hh);
        }
    }
}

// ------- launch 2: per-block local scan -> rloc + att1v ----------------------
__global__ __launch_bounds__(1024) void scanA_att_k(
    const int* __restrict__ deg, int* __restrict__ rloc, int* __restrict__ bsum,
    int N, int NBLK,
    const float* __restrict__ x, const float* __restrict__ UV4,
    float* __restrict__ a_src, float* __restrict__ a_dst)
{
    if ((int)blockIdx.x < NBLK) {
        __shared__ int wsum[16];
        int t = threadIdx.x, lane = t & 63, w = t >> 6;
        int i = blockIdx.x * 1024 + t;
        int v = (i < N) ? deg[i] : 0;
        int incl = v;
        #pragma unroll
        for (int o = 1; o < 64; o <<= 1) {
            int nb = __shfl_up(incl, o);
            if (lane >= o) incl += nb;
        }
        if (lane == 63) wsum[w] = incl;
        __syncthreads();
        if (w == 0 && lane < 16) {
            int s = wsum[lane];
            #pragma unroll
            for (int o = 1; o < 16; o <<= 1) {
                int nb = __shfl_up(s, o);
                if (lane >= o) s += nb;
            }
            wsum[lane] = s;
        }
        __syncthreads();
        int woff = (w == 0) ? 0 : wsum[w - 1];
        if (i < N) rloc[i] = woff + incl - v;
        if (t == 1023) bsum[blockIdx.x] = woff + incl;
    } else {
        int wave = threadIdx.x >> 6, lane = threadIdx.x & 63;
        int n = ((int)blockIdx.x - NBLK) * 16 + wave;
        if (n >= N) return;
        float2 xv = ((const float2*)(x + (long)n * IN_F))[lane];
        float4 u0 = ((const float4*)UV4)[2 * lane];
        float4 u1 = ((const float4*)UV4)[2 * lane + 1];
        float p0 = xv.x * u0.x + xv.y * u1.x;
        float p1 = xv.x * u0.y + xv.y * u1.y;
        float p2 = xv.x * u0.z + xv.y * u1.z;
        float p3 = xv.x * u0.w + xv.y * u1.w;
        #pragma unroll
        for (int o = 32; o > 0; o >>= 1) {
            p0 += __shfl_xor(p0, o); p1 += __shfl_xor(p1, o);
            p2 += __shfl_xor(p2, o); p3 += __shfl_xor(p3, o);
        }
        if (lane == 0) {
            a_src[(long)n * 2 + 0] = p0; a_src[(long)n * 2 + 1] = p1;
            a_dst[(long)n * 2 + 0] = p2; a_dst[(long)n * 2 + 1] = p3;
        }
    }
}

// ------- launch 3 (fused): rowptr fixup + atomic-free scatter ----------------
__global__ __launch_bounds__(1024) void scat_fix_k(
    const int* __restrict__ ei_s, const int* __restrict__ ei_d,
    const int* __restrict__ rloc, const int* __restrict__ bsum,
    const int* __restrict__ pos, int* __restrict__ rowptr,
    int* __restrict__ csr_src, int* __restrict__ csr_eid,
    int E, int Ep, int N, int NBLK)
{
    __shared__ int bexs[64];
    __shared__ int tot_sh;
    int t = threadIdx.x;
    if (t < 64) {
        int v = (t < NBLK) ? bsum[t] : 0;
        int incl = v;
        #pragma unroll
        for (int o = 1; o < 64; o <<= 1) {
            int nb = __shfl_up(incl, o);
            if (t >= o) incl += nb;
        }
        bexs[t] = incl - v;
        if (t == NBLK - 1) tot_sh = incl;
    }
    __syncthreads();
    if ((int)blockIdx.x < NBLK) {
        int i = blockIdx.x * 1024 + t;
        if (i < N) rowptr[i] = rloc[i] + bexs[blockIdx.x];
        if ((int)blockIdx.x == NBLK - 1 && t == 0) rowptr[N] = tot_sh;
    } else {
        int i = ((int)blockIdx.x - NBLK) * 1024 + t;
        if (i >= Ep) return;
        int s = (i < E) ? ei_s[i] : (i - E);
        int d = (i < E) ? ei_d[i] : (i - E);
        int at = rloc[d] + bexs[d >> 10] + pos[i];
        csr_src[at] = s;
        csr_eid[at] = (i < E) ? i : -1;
    }
}

// ------- layer-1 aggregation in INPUT space; emits split-f16 G ---------------
__global__ __launch_bounds__(256) void agg1x(
    const int* __restrict__ rowptr, const int* __restrict__ csr_src,
    const float* __restrict__ a_s, const float* __restrict__ a_d,  // [N,2]
    const float* __restrict__ x, _Float16* __restrict__ Gh,
    _Float16* __restrict__ Gl, int N)
{
    int wave = threadIdx.x >> 6, lane = threadIdx.x & 63;
    int d = blockIdx.x * 4 + wave;
    if (d >= N) return;
    int row = rowptr[d], end = rowptr[d + 1];
    int h = lane >> 5, l5 = lane & 31;
    float adh = a_d[(long)d * 2 + h];
    float a0[4] = {0,0,0,0}, a1[4] = {0,0,0,0};
    float den = 0.f;
    for (int base = row; base < end; base += 32) {
        int cnt = min(32, end - base);
        int sreg = 0; float e = 0.f;
        if (l5 < cnt) {
            sreg = csr_src[base + l5];
            float v = a_s[(long)sreg * 2 + h] + adh;
            v = (v > 0.f) ? v : NEG * v;
            e = expf(v);
            den += e;
        }
        int jmax = (cnt + 1) >> 1;
        for (int j = 0; j < jmax; ++j) {
            int m = 2 * j + h;
            int s = __shfl(sreg, m);
            float w0 = __shfl(e, m);
            float w1 = __shfl(e, 32 | m);
            float4 v = *(const float4*)(x + (long)s * IN_F + l5 * 4);
            a0[0] = fmaf(w0, v.x, a0[0]); a0[1] = fmaf(w0, v.y, a0[1]);
            a0[2] = fmaf(w0, v.z, a0[2]); a0[3] = fmaf(w0, v.w, a0[3]);
            a1[0] = fmaf(w1, v.x, a1[0]); a1[1] = fmaf(w1, v.y, a1[1]);
            a1[2] = fmaf(w1, v.z, a1[2]); a1[3] = fmaf(w1, v.w, a1[3]);
        }
    }
    #pragma unroll
    for (int o = 16; o > 0; o >>= 1) den += __shfl_xor(den, o);
    #pragma unroll
    for (int p = 0; p < 4; ++p) {
        a0[p] += __shfl_xor(a0[p], 32);
        a1[p] += __shfl_xor(a1[p], 32);
    }
    float inv = 1.0f / (den + 1e-16f);
    float* acch = (h == 0) ? a0 : a1;
    f16x4 hi, lo;
    #pragma unroll
    for (int p = 0; p < 4; ++p) {
        float v = acch[p] * inv;
        hi[p] = (_Float16)v;
        lo[p] = (_Float16)(v - (float)hi[p]);
    }
    long base = (long)d * F1 + h * 128 + l5 * 4;
    *(f16x4*)(Gh + base) = hi;
    *(f16x4*)(Gl + base) = lo;
}

// ------- layer-2 aggregation (bias fused into output) ------------------------
__global__ __launch_bounds__(256) void agg2_csr(
    const int* __restrict__ rowptr, const int* __restrict__ csr_src,
    const float* __restrict__ a_s, const float* __restrict__ a_d,  // [N]
    const float* __restrict__ xh2, const float* __restrict__ b2,
    float* __restrict__ out2b, int N)
{
    int wave = threadIdx.x >> 6, lane = threadIdx.x & 63;
    int d = blockIdx.x * 4 + wave;
    if (d >= N) return;
    int row = rowptr[d], end = rowptr[d + 1];
    float adv = a_d[d];
    int g = lane >> 4, q = lane & 15;
    float acc[4] = {0,0,0,0};
    float den = 0.f;
    for (int base = row; base < end; base += 64) {
        int cnt = min(64, end - base);
        float ev = 0.f; int sreg = 0;
        if (lane < cnt) {
            sreg = csr_src[base + lane];
            float v = a_s[sreg] + adv; v = (v > 0.f) ? v : NEG * v;
            ev = expf(v);
            den += ev;
        }
        int jmax = (cnt + 3) >> 2;
        for (int j = 0; j < jmax; ++j) {
            int m = 4 * j + g;
            int s = __shfl(sreg, m);
            float w = __shfl(ev, m);
            float4 v = *(const float4*)(xh2 + (long)s * F2 + q * 4);
            acc[0] = fmaf(w, v.x, acc[0]); acc[1] = fmaf(w, v.y, acc[1]);
            acc[2] = fmaf(w, v.z, acc[2]); acc[3] = fmaf(w, v.w, acc[3]);
        }
    }
    #pragma unroll
    for (int o = 32; o > 0; o >>= 1) den += __shfl_xor(den, o);
    #pragma unroll
    for (int p = 0; p < 4; ++p) {
        acc[p] += __shfl_xor(acc[p], 16);
        acc[p] += __shfl_xor(acc[p], 32);
    }
    if (g == 0) {
        float inv = 1.0f / (den + 1e-16f);
        float4 bb = *(const float4*)&b2[q * 4];
        float4 o4 = {acc[0] * inv + bb.x, acc[1] * inv + bb.y,
                     acc[2] * inv + bb.z, acc[3] * inv + bb.w};
        *(float4*)(out2b + (long)d * F2 + q * 4) = o4;
    }
}

// ------- decode via CSR ------------------------------------------------------
__global__ __launch_bounds__(256) void decode_csr(
    const int* __restrict__ rowptr, const int* __restrict__ csr_src,
    const int* __restrict__ csr_eid, const float* __restrict__ z2b,
    float* __restrict__ out, int N)
{
    int wave = threadIdx.x >> 6, lane = threadIdx.x & 63;
    int d = blockIdx.x * 4 + wave;
    if (d >= N) return;
    int row = rowptr[d], end = rowptr[d + 1];
    int g = lane >> 4, q = lane & 15;
    float4 vd = *(const float4*)(z2b + (long)d * F2 + q * 4);
    for (int base = row; base < end; base += 64) {
        int cnt = min(64, end - base);
        int sreg = 0, ereg = -1;
        if (lane < cnt) {
            sreg = csr_src[base + lane];
            ereg = csr_eid[base + lane];
        }
        int jmax = (cnt + 3) >> 2;
        for (int j = 0; j < jmax; ++j) {
            int m = 4 * j + g;
            int s = __shfl(sreg, m);
            int eid = __shfl(ereg, m);
            float4 vs = *(const float4*)(z2b + (long)s * F2 + q * 4);
            float p = vd.x * vs.x + vd.y * vs.y + vd.z * vs.z + vd.w * vs.w;
            #pragma unroll
            for (int o = 1; o < 16; o <<= 1) p += __shfl_xor(p, o);
            if (q == 0 && eid >= 0) out[eid] = p;
        }
    }
}

extern "C" void kernel_launch(void* const* d_in, const int* in_sizes, int n_in,
                              void* d_out, int out_size, void* d_ws, size_t ws_size,
                              hipStream_t stream) {
    const float* x   = (const float*)d_in[0];
    const int*   ei  = (const int*)d_in[1];
    const float* W1  = (const float*)d_in[2];
    const float* as1 = (const float*)d_in[3];
    const float* ad1 = (const float*)d_in[4];
    const float* b1  = (const float*)d_in[5];
    const float* W2  = (const float*)d_in[6];
    const float* as2 = (const float*)d_in[7];
    const float* ad2 = (const float*)d_in[8];
    const float* b2  = (const float*)d_in[9];

    int N  = in_sizes[0] / IN_F;   // 50000
    int E  = in_sizes[1] / 2;      // 600000
    int Ep = E + N;
    const int* ei_src = ei;
    const int* ei_dst = ei + E;

    float* ws = (float*)d_ws;
    size_t off = 0;
    auto alloc = [&](size_t n) { float* p = ws + off; off += (n + 63) & ~(size_t)63; return p; };

    _Float16* Gh  = (_Float16*)alloc((size_t)N * F1 / 2);
    _Float16* Gl  = (_Float16*)alloc((size_t)N * F1 / 2);
    _Float16* Wth = (_Float16*)alloc(IN_F * F1 / 2);
    _Float16* Wtl = (_Float16*)alloc(IN_F * F1 / 2);
    float* z1     = alloc((size_t)N * F1);
    float* xh2    = alloc((size_t)N * F2);
    float* out2b  = alloc((size_t)N * F2);
    float* a_src1 = alloc((size_t)N * H1);
    float* a_dst1 = alloc((size_t)N * H1);
    float* a_src2 = alloc(N);
    float* a_dst2 = alloc(N);
    float* UV4    = alloc(IN_F * 4);
    int* rowptr   = (int*)alloc(N + 64);
    int* rloc     = (int*)alloc(N + 64);
    int* csr_src  = (int*)alloc(Ep);
    int* csr_eid  = (int*)alloc(Ep);
    int* pos      = (int*)alloc(Ep);
    int* bsum     = (int*)alloc(64);
    int* deg      = (int*)alloc(N);
    hipMemsetAsync(deg, 0, (size_t)N * sizeof(int), stream);

    int NBLK = (N + 1023) / 1024;       // 49
    int NBH  = (Ep + 255) / 256;
    int NBS  = (Ep + 1023) / 1024;
    int NBA  = (N + 15) / 16;

    hist_uv_k<<<NBH + 2, 256, 0, stream>>>(ei_dst, deg, pos, E, Ep, NBH,
                                           W1, as1, ad1, UV4, Wth, Wtl);
    scanA_att_k<<<NBLK + NBA, 1024, 0, stream>>>(deg, rloc, bsum, N, NBLK,
                                                 x, UV4, a_src1, a_dst1);
    scat_fix_k<<<NBLK + NBS, 1024, 0, stream>>>(ei_src, ei_dst, rloc, bsum, pos,
                                                rowptr, csr_src, csr_eid,
                                                E, Ep, N, NBLK);

    // layer 1: aggregate x into split-f16 G, then row-resident MFMA GEMM
    agg1x<<<(N + 3) / 4, 256, 0, stream>>>(rowptr, csr_src, a_src1, a_dst1, x,
                                           Gh, Gl, N);
    gemm1_mfma<<<(N + 63) / 64, 256, 0, stream>>>(Gh, Gl, Wth, Wtl, z1, N);

    // layer 2 (vector GEMM, relu+bias staged, att epilogue)
    int mt1 = (N + 127) / 128;
    gemm_tiled<F1, 128, 64, 4, 8, F1, F2, F2, true, true, false>
        <<<dim3(mt1, 1), 256, 0, stream>>>(
        z1, b1, W2, xh2, as2, ad2, a_src2, a_dst2, N);
    agg2_csr<<<(N + 3) / 4, 256, 0, stream>>>(rowptr, csr_src, a_src2, a_dst2, xh2, b2, out2b, N);

    // decode via CSR
    decode_csr<<<(N + 3) / 4, 256, 0, stream>>>(rowptr, csr_src, csr_eid, out2b,
                                                (float*)d_out, N);
}

// Round 16
// 332.825 us; speedup vs baseline: 1.1534x; 1.1293x over previous
//
#include <hip/hip_runtime.h>
#include <math.h>

#define IN_F 128
#define F1 256   // H1*C1
#define H1 2
#define F2 64
#define NEG 0.2f

typedef _Float16 f16x8 __attribute__((ext_vector_type(8)));
typedef _Float16 f16x4 __attribute__((ext_vector_type(4)));
typedef float f32x4 __attribute__((ext_vector_type(4)));

// ---------------- tiled fp32 GEMM (round-9 best) — used for layer 2 ----------
template<int KTOT, int TM, int TN, int RM, int RN, int LDA, int LDW, int LDC,
         bool RELU, bool ATT_EP, bool HEADOFF>
__global__ __launch_bounds__(256) void gemm_tiled(
    const float* __restrict__ A, const float* __restrict__ bias,
    const float* __restrict__ W, float* __restrict__ C,
    const float* __restrict__ att_s, const float* __restrict__ att_d,
    float* __restrict__ a_src, float* __restrict__ a_dst, int M)
{
    constexpr int NX = TN / RN;
    constexpr int NY = 256 / NX;
    static_assert(NY * RM == TM, "tile mismatch");
    static_assert(RN == 8, "split-col mapping assumes RN==8");
    __shared__ float As[32][TM];
    __shared__ float Ws[32][TN];
    int t = threadIdx.x;
    int tx = t % NX, ty = t / NX;
    int m0 = blockIdx.x * TM;
    int n0 = blockIdx.y * TN;
    long aoff = HEADOFF ? (long)blockIdx.y * KTOT : 0;
    float acc[RM][RN];
    #pragma unroll
    for (int i = 0; i < RM; ++i)
        #pragma unroll
        for (int j = 0; j < RN; ++j) acc[i][j] = 0.f;

    constexpr int PARTS = 256 / TM;
    constexpr int F4PT = 8 / PARTS;
    int ar = t % TM, apart = t / TM;
    int arow = m0 + ar; if (arow >= M) arow = M - 1;
    constexpr int WTPK = TN / 4;
    constexpr int WKP = 256 / WTPK;
    int wk0 = t / WTPK, wc = t % WTPK;

    for (int kc = 0; kc < KTOT; kc += 32) {
        const float* ap = A + (long)arow * LDA + aoff + kc + apart * (F4PT * 4);
        #pragma unroll
        for (int p = 0; p < F4PT; ++p) {
            int kk = apart * (F4PT * 4) + p * 4;
            float4 v = *(const float4*)(ap + p * 4);
            if (RELU) {
                float4 bb = *(const float4*)&bias[kc + kk];
                v.x = fmaxf(v.x + bb.x, 0.f);
                v.y = fmaxf(v.y + bb.y, 0.f);
                v.z = fmaxf(v.z + bb.z, 0.f);
                v.w = fmaxf(v.w + bb.w, 0.f);
            }
            As[kk + 0][ar] = v.x;
            As[kk + 1][ar] = v.y;
            As[kk + 2][ar] = v.z;
            As[kk + 3][ar] = v.w;
        }
        #pragma unroll
        for (int p = 0; p < 32 / WKP; ++p) {
            int k = wk0 + p * WKP;
            *(float4*)&Ws[k][wc * 4] =
                *(const float4*)&W[(long)(kc + k) * LDW + n0 + wc * 4];
        }
        __syncthreads();
        #pragma unroll 4
        for (int k = 0; k < 32; ++k) {
            float av[RM], wv[RN];
            #pragma unroll
            for (int i4 = 0; i4 < RM / 4; ++i4) {
                float4 v = *(const float4*)&As[k][ty * RM + i4 * 4];
                av[i4 * 4 + 0] = v.x; av[i4 * 4 + 1] = v.y;
                av[i4 * 4 + 2] = v.z; av[i4 * 4 + 3] = v.w;
            }
            {
                float4 v = *(const float4*)&Ws[k][tx * 4];
                wv[0] = v.x; wv[1] = v.y; wv[2] = v.z; wv[3] = v.w;
                float4 u = *(const float4*)&Ws[k][TN / 2 + tx * 4];
                wv[4] = u.x; wv[5] = u.y; wv[6] = u.z; wv[7] = u.w;
            }
            #pragma unroll
            for (int i = 0; i < RM; ++i)
                #pragma unroll
                for (int j = 0; j < RN; ++j)
                    acc[i][j] = fmaf(av[i], wv[j], acc[i][j]);
        }
        __syncthreads();
    }
    #pragma unroll
    for (int i = 0; i < RM; ++i) {
        int row = m0 + ty * RM + i;
        if (row < M) {
            float4 o0 = {acc[i][0], acc[i][1], acc[i][2], acc[i][3]};
            float4 o1 = {acc[i][4], acc[i][5], acc[i][6], acc[i][7]};
            *(float4*)&C[(long)row * LDC + n0 + tx * 4] = o0;
            *(float4*)&C[(long)row * LDC + n0 + TN / 2 + tx * 4] = o1;
        }
    }
    if (ATT_EP) {
        float asr[RN], adr[RN];
        #pragma unroll
        for (int j = 0; j < RN; ++j) {
            int col = (j < 4) ? (tx * 4 + j) : (TN / 2 + tx * 4 + j - 4);
            asr[j] = att_s[col];
            adr[j] = att_d[col];
        }
        #pragma unroll
        for (int i = 0; i < RM; ++i) {
            float ps = 0.f, pd = 0.f;
            #pragma unroll
            for (int j = 0; j < RN; ++j) {
                ps = fmaf(acc[i][j], asr[j], ps);
                pd = fmaf(acc[i][j], adr[j], pd);
            }
            #pragma unroll
            for (int o = 1; o < NX; o <<= 1) {
                ps += __shfl_xor(ps, o);
                pd += __shfl_xor(pd, o);
            }
            int row = m0 + ty * RM + i;
            if (tx == 0 && row < M) { a_src[row] = ps; a_dst[row] = pd; }
        }
    }
}

// ------- layer-1 GEMM via split-f16 MFMA, LDS-fragment B ---------------------
// One head per block (blockIdx.y). B pre-swizzled into MFMA-frag layout in
// LDS: Bfrag[(ct*4+ks)*64+lane] -> lane-linear 16B ds_reads (~12cyc,
// conflict-free) instead of round 15's ~300cyc L2 loads per col-tile. 8
// independent ct accumulator chains (fully unrolled) keep the MFMA pipe fed.
// G read exactly once (64KB LDS -> 2 blocks/CU -> 8 waves/CU).
__global__ __launch_bounds__(256) void gemm1_mfma(
    const _Float16* __restrict__ Gh, const _Float16* __restrict__ Gl,
    const _Float16* __restrict__ Wth, const _Float16* __restrict__ Wtl,
    float* __restrict__ z1, int N)
{
    __shared__ _Float16 BhF[32 * 64 * 8];   // 32 KB: [ct*4+ks][lane][8]
    __shared__ _Float16 BlF[32 * 64 * 8];   // 32 KB
    int t = threadIdx.x;
    int h = blockIdx.y;
    // stage B into fragment layout
    const _Float16* wsh = Wth + (long)h * 128 * IN_F;
    const _Float16* wsl = Wtl + (long)h * 128 * IN_F;
    #pragma unroll
    for (int p = 0; p < 8; ++p) {
        int fs = p * 256 + t;            // 0..2047 fragment slots
        int lane = fs & 63;
        int slot = fs >> 6;              // ct*4+ks
        int ct = slot >> 2, ks = slot & 3;
        int col = ct * 16 + (lane & 15);
        int koff = ks * 32 + (lane >> 4) * 8;
        *(f16x8*)&BhF[fs * 8] = *(const f16x8*)&wsh[(long)col * IN_F + koff];
        *(f16x8*)&BlF[fs * 8] = *(const f16x8*)&wsl[(long)col * IN_F + koff];
    }
    __syncthreads();

    int wave = t >> 6, lane = t & 63;
    int quad = lane >> 4, l4 = lane & 15;
    int rt = blockIdx.x * 4 + wave;      // row-tile of 16
    if (rt * 16 >= N) return;            // N%16==0: no partial tiles
    long mrow = (long)rt * 16 + l4;
    const _Float16* gh = Gh + mrow * F1 + h * 128 + quad * 8;
    const _Float16* gl = Gl + mrow * F1 + h * 128 + quad * 8;
    f16x8 ah[4], al[4];
    #pragma unroll
    for (int ks = 0; ks < 4; ++ks) {
        ah[ks] = *(const f16x8*)(gh + ks * 32);
        al[ks] = *(const f16x8*)(gl + ks * 32);
    }
    f32x4 acc[8];
    #pragma unroll
    for (int ct = 0; ct < 8; ++ct) acc[ct] = (f32x4){0.f, 0.f, 0.f, 0.f};
    #pragma unroll
    for (int ks = 0; ks < 4; ++ks) {
        #pragma unroll
        for (int ct = 0; ct < 8; ++ct) {
            f16x8 bh = *(const f16x8*)&BhF[((ct * 4 + ks) * 64 + lane) * 8];
            f16x8 bl = *(const f16x8*)&BlF[((ct * 4 + ks) * 64 + lane) * 8];
            acc[ct] = __builtin_amdgcn_mfma_f32_16x16x32_f16(ah[ks], bh, acc[ct], 0, 0, 0);
            acc[ct] = __builtin_amdgcn_mfma_f32_16x16x32_f16(al[ks], bh, acc[ct], 0, 0, 0);
            acc[ct] = __builtin_amdgcn_mfma_f32_16x16x32_f16(ah[ks], bl, acc[ct], 0, 0, 0);
        }
    }
    int rbase = rt * 16 + quad * 4;
    #pragma unroll
    for (int ct = 0; ct < 8; ++ct) {
        int col = h * 128 + ct * 16 + l4;
        #pragma unroll
        for (int i = 0; i < 4; ++i)
            z1[(long)(rbase + i) * F1 + col] = acc[ct][i];
    }
}

// ------- launch 1: histogram + UV precompute + W1 transpose/split ------------
__global__ __launch_bounds__(256) void hist_uv_k(
    const int* __restrict__ ei_d, int* __restrict__ deg, int* __restrict__ pos,
    int E, int Ep, int NBH,
    const float* __restrict__ W1, const float* __restrict__ as1,
    const float* __restrict__ ad1, float* __restrict__ UV4,
    _Float16* __restrict__ Wth, _Float16* __restrict__ Wtl)
{
    if ((int)blockIdx.x < NBH) {
        int i = blockIdx.x * 256 + threadIdx.x;
        if (i >= Ep) return;
        int d = (i < E) ? ei_d[i] : (i - E);
        pos[i] = atomicAdd(&deg[d], 1);
    } else if ((int)blockIdx.x == NBH) {
        int t = threadIdx.x;
        int k = t >> 1, h = t & 1;
        const float* wrow = W1 + (long)k * F1 + h * 128;
        const float* sa = as1 + h * 128;
        const float* da = ad1 + h * 128;
        float u = 0.f, v = 0.f;
        for (int c = 0; c < 128; ++c) {
            float w = wrow[c];
            u = fmaf(w, sa[c], u);
            v = fmaf(w, da[c], v);
        }
        UV4[k * 4 + h] = u;
        UV4[k * 4 + 2 + h] = v;
    } else {
        int n = threadIdx.x;
        for (int k = 0; k < IN_F; ++k) {
            float w = W1[(long)k * F1 + n];
            _Float16 hh = (_Float16)w;
            Wth[(long)n * IN_F + k] = hh;
            Wtl[(long)n * IN_F + k] = (_Float16)(w - (float)hh);
        }
    }
}

// ------- launch 2: per-block local scan -> rloc + att1v ----------------------
__global__ __launch_bounds__(1024) void scanA_att_k(
    const int* __restrict__ deg, int* __restrict__ rloc, int* __restrict__ bsum,
    int N, int NBLK,
    const float* __restrict__ x, const float* __restrict__ UV4,
    float* __restrict__ a_src, float* __restrict__ a_dst)
{
    if ((int)blockIdx.x < NBLK) {
        __shared__ int wsum[16];
        int t = threadIdx.x, lane = t & 63, w = t >> 6;
        int i = blockIdx.x * 1024 + t;
        int v = (i < N) ? deg[i] : 0;
        int incl = v;
        #pragma unroll
        for (int o = 1; o < 64; o <<= 1) {
            int nb = __shfl_up(incl, o);
            if (lane >= o) incl += nb;
        }
        if (lane == 63) wsum[w] = incl;
        __syncthreads();
        if (w == 0 && lane < 16) {
            int s = wsum[lane];
            #pragma unroll
            for (int o = 1; o < 16; o <<= 1) {
                int nb = __shfl_up(s, o);
                if (lane >= o) s += nb;
            }
            wsum[lane] = s;
        }
        __syncthreads();
        int woff = (w == 0) ? 0 : wsum[w - 1];
        if (i < N) rloc[i] = woff + incl - v;
        if (t == 1023) bsum[blockIdx.x] = woff + incl;
    } else {
        int wave = threadIdx.x >> 6, lane = threadIdx.x & 63;
        int n = ((int)blockIdx.x - NBLK) * 16 + wave;
        if (n >= N) return;
        float2 xv = ((const float2*)(x + (long)n * IN_F))[lane];
        float4 u0 = ((const float4*)UV4)[2 * lane];
        float4 u1 = ((const float4*)UV4)[2 * lane + 1];
        float p0 = xv.x * u0.x + xv.y * u1.x;
        float p1 = xv.x * u0.y + xv.y * u1.y;
        float p2 = xv.x * u0.z + xv.y * u1.z;
        float p3 = xv.x * u0.w + xv.y * u1.w;
        #pragma unroll
        for (int o = 32; o > 0; o >>= 1) {
            p0 += __shfl_xor(p0, o); p1 += __shfl_xor(p1, o);
            p2 += __shfl_xor(p2, o); p3 += __shfl_xor(p3, o);
        }
        if (lane == 0) {
            a_src[(long)n * 2 + 0] = p0; a_src[(long)n * 2 + 1] = p1;
            a_dst[(long)n * 2 + 0] = p2; a_dst[(long)n * 2 + 1] = p3;
        }
    }
}

// ------- launch 3 (fused): rowptr fixup + atomic-free scatter ----------------
__global__ __launch_bounds__(1024) void scat_fix_k(
    const int* __restrict__ ei_s, const int* __restrict__ ei_d,
    const int* __restrict__ rloc, const int* __restrict__ bsum,
    const int* __restrict__ pos, int* __restrict__ rowptr,
    int* __restrict__ csr_src, int* __restrict__ csr_eid,
    int E, int Ep, int N, int NBLK)
{
    __shared__ int bexs[64];
    __shared__ int tot_sh;
    int t = threadIdx.x;
    if (t < 64) {
        int v = (t < NBLK) ? bsum[t] : 0;
        int incl = v;
        #pragma unroll
        for (int o = 1; o < 64; o <<= 1) {
            int nb = __shfl_up(incl, o);
            if (t >= o) incl += nb;
        }
        bexs[t] = incl - v;
        if (t == NBLK - 1) tot_sh = incl;
    }
    __syncthreads();
    if ((int)blockIdx.x < NBLK) {
        int i = blockIdx.x * 1024 + t;
        if (i < N) rowptr[i] = rloc[i] + bexs[blockIdx.x];
        if ((int)blockIdx.x == NBLK - 1 && t == 0) rowptr[N] = tot_sh;
    } else {
        int i = ((int)blockIdx.x - NBLK) * 1024 + t;
        if (i >= Ep) return;
        int s = (i < E) ? ei_s[i] : (i - E);
        int d = (i < E) ? ei_d[i] : (i - E);
        int at = rloc[d] + bexs[d >> 10] + pos[i];
        csr_src[at] = s;
        csr_eid[at] = (i < E) ? i : -1;
    }
}

// ------- layer-1 aggregation in INPUT space; emits split-f16 G ---------------
__global__ __launch_bounds__(256) void agg1x(
    const int* __restrict__ rowptr, const int* __restrict__ csr_src,
    const float* __restrict__ a_s, const float* __restrict__ a_d,  // [N,2]
    const float* __restrict__ x, _Float16* __restrict__ Gh,
    _Float16* __restrict__ Gl, int N)
{
    int wave = threadIdx.x >> 6, lane = threadIdx.x & 63;
    int d = blockIdx.x * 4 + wave;
    if (d >= N) return;
    int row = rowptr[d], end = rowptr[d + 1];
    int h = lane >> 5, l5 = lane & 31;
    float adh = a_d[(long)d * 2 + h];
    float a0[4] = {0,0,0,0}, a1[4] = {0,0,0,0};
    float den = 0.f;
    for (int base = row; base < end; base += 32) {
        int cnt = min(32, end - base);
        int sreg = 0; float e = 0.f;
        if (l5 < cnt) {
            sreg = csr_src[base + l5];
            float v = a_s[(long)sreg * 2 + h] + adh;
            v = (v > 0.f) ? v : NEG * v;
            e = expf(v);
            den += e;
        }
        int jmax = (cnt + 1) >> 1;
        for (int j = 0; j < jmax; ++j) {
            int m = 2 * j + h;
            int s = __shfl(sreg, m);
            float w0 = __shfl(e, m);
            float w1 = __shfl(e, 32 | m);
            float4 v = *(const float4*)(x + (long)s * IN_F + l5 * 4);
            a0[0] = fmaf(w0, v.x, a0[0]); a0[1] = fmaf(w0, v.y, a0[1]);
            a0[2] = fmaf(w0, v.z, a0[2]); a0[3] = fmaf(w0, v.w, a0[3]);
            a1[0] = fmaf(w1, v.x, a1[0]); a1[1] = fmaf(w1, v.y, a1[1]);
            a1[2] = fmaf(w1, v.z, a1[2]); a1[3] = fmaf(w1, v.w, a1[3]);
        }
    }
    #pragma unroll
    for (int o = 16; o > 0; o >>= 1) den += __shfl_xor(den, o);
    #pragma unroll
    for (int p = 0; p < 4; ++p) {
        a0[p] += __shfl_xor(a0[p], 32);
        a1[p] += __shfl_xor(a1[p], 32);
    }
    float inv = 1.0f / (den + 1e-16f);
    float* acch = (h == 0) ? a0 : a1;
    f16x4 hi, lo;
    #pragma unroll
    for (int p = 0; p < 4; ++p) {
        float v = acch[p] * inv;
        hi[p] = (_Float16)v;
        lo[p] = (_Float16)(v - (float)hi[p]);
    }
    long base = (long)d * F1 + h * 128 + l5 * 4;
    *(f16x4*)(Gh + base) = hi;
    *(f16x4*)(Gl + base) = lo;
}

// ------- layer-2 aggregation (bias fused into output) ------------------------
__global__ __launch_bounds__(256) void agg2_csr(
    const int* __restrict__ rowptr, const int* __restrict__ csr_src,
    const float* __restrict__ a_s, const float* __restrict__ a_d,  // [N]
    const float* __restrict__ xh2, const float* __restrict__ b2,
    float* __restrict__ out2b, int N)
{
    int wave = threadIdx.x >> 6, lane = threadIdx.x & 63;
    int d = blockIdx.x * 4 + wave;
    if (d >= N) return;
    int row = rowptr[d], end = rowptr[d + 1];
    float adv = a_d[d];
    int g = lane >> 4, q = lane & 15;
    float acc[4] = {0,0,0,0};
    float den = 0.f;
    for (int base = row; base < end; base += 64) {
        int cnt = min(64, end - base);
        float ev = 0.f; int sreg = 0;
        if (lane < cnt) {
            sreg = csr_src[base + lane];
            float v = a_s[sreg] + adv; v = (v > 0.f) ? v : NEG * v;
            ev = expf(v);
            den += ev;
        }
        int jmax = (cnt + 3) >> 2;
        for (int j = 0; j < jmax; ++j) {
            int m = 4 * j + g;
            int s = __shfl(sreg, m);
            float w = __shfl(ev, m);
            float4 v = *(const float4*)(xh2 + (long)s * F2 + q * 4);
            acc[0] = fmaf(w, v.x, acc[0]); acc[1] = fmaf(w, v.y, acc[1]);
            acc[2] = fmaf(w, v.z, acc[2]); acc[3] = fmaf(w, v.w, acc[3]);
        }
    }
    #pragma unroll
    for (int o = 32; o > 0; o >>= 1) den += __shfl_xor(den, o);
    #pragma unroll
    for (int p = 0; p < 4; ++p) {
        acc[p] += __shfl_xor(acc[p], 16);
        acc[p] += __shfl_xor(acc[p], 32);
    }
    if (g == 0) {
        float inv = 1.0f / (den + 1e-16f);
        float4 bb = *(const float4*)&b2[q * 4];
        float4 o4 = {acc[0] * inv + bb.x, acc[1] * inv + bb.y,
                     acc[2] * inv + bb.z, acc[3] * inv + bb.w};
        *(float4*)(out2b + (long)d * F2 + q * 4) = o4;
    }
}

// ------- decode via CSR ------------------------------------------------------
__global__ __launch_bounds__(256) void decode_csr(
    const int* __restrict__ rowptr, const int* __restrict__ csr_src,
    const int* __restrict__ csr_eid, const float* __restrict__ z2b,
    float* __restrict__ out, int N)
{
    int wave = threadIdx.x >> 6, lane = threadIdx.x & 63;
    int d = blockIdx.x * 4 + wave;
    if (d >= N) return;
    int row = rowptr[d], end = rowptr[d + 1];
    int g = lane >> 4, q = lane & 15;
    float4 vd = *(const float4*)(z2b + (long)d * F2 + q * 4);
    for (int base = row; base < end; base += 64) {
        int cnt = min(64, end - base);
        int sreg = 0, ereg = -1;
        if (lane < cnt) {
            sreg = csr_src[base + lane];
            ereg = csr_eid[base + lane];
        }
        int jmax = (cnt + 3) >> 2;
        for (int j = 0; j < jmax; ++j) {
            int m = 4 * j + g;
            int s = __shfl(sreg, m);
            int eid = __shfl(ereg, m);
            float4 vs = *(const float4*)(z2b + (long)s * F2 + q * 4);
            float p = vd.x * vs.x + vd.y * vs.y + vd.z * vs.z + vd.w * vs.w;
            #pragma unroll
            for (int o = 1; o < 16; o <<= 1) p += __shfl_xor(p, o);
            if (q == 0 && eid >= 0) out[eid] = p;
        }
    }
}

extern "C" void kernel_launch(void* const* d_in, const int* in_sizes, int n_in,
                              void* d_out, int out_size, void* d_ws, size_t ws_size,
                              hipStream_t stream) {
    const float* x   = (const float*)d_in[0];
    const int*   ei  = (const int*)d_in[1];
    const float* W1  = (const float*)d_in[2];
    const float* as1 = (const float*)d_in[3];
    const float* ad1 = (const float*)d_in[4];
    const float* b1  = (const float*)d_in[5];
    const float* W2  = (const float*)d_in[6];
    const float* as2 = (const float*)d_in[7];
    const float* ad2 = (const float*)d_in[8];
    const float* b2  = (const float*)d_in[9];

    int N  = in_sizes[0] / IN_F;   // 50000
    int E  = in_sizes[1] / 2;      // 600000
    int Ep = E + N;
    const int* ei_src = ei;
    const int* ei_dst = ei + E;

    float* ws = (float*)d_ws;
    size_t off = 0;
    auto alloc = [&](size_t n) { float* p = ws + off; off += (n + 63) & ~(size_t)63; return p; };

    _Float16* Gh  = (_Float16*)alloc((size_t)N * F1 / 2);
    _Float16* Gl  = (_Float16*)alloc((size_t)N * F1 / 2);
    _Float16* Wth = (_Float16*)alloc(IN_F * F1 / 2);
    _Float16* Wtl = (_Float16*)alloc(IN_F * F1 / 2);
    float* z1     = alloc((size_t)N * F1);
    float* xh2    = alloc((size_t)N * F2);
    float* out2b  = alloc((size_t)N * F2);
    float* a_src1 = alloc((size_t)N * H1);
    float* a_dst1 = alloc((size_t)N * H1);
    float* a_src2 = alloc(N);
    float* a_dst2 = alloc(N);
    float* UV4    = alloc(IN_F * 4);
    int* rowptr   = (int*)alloc(N + 64);
    int* rloc     = (int*)alloc(N + 64);
    int* csr_src  = (int*)alloc(Ep);
    int* csr_eid  = (int*)alloc(Ep);
    int* pos      = (int*)alloc(Ep);
    int* bsum     = (int*)alloc(64);
    int* deg      = (int*)alloc(N);
    hipMemsetAsync(deg, 0, (size_t)N * sizeof(int), stream);

    int NBLK = (N + 1023) / 1024;       // 49
    int NBH  = (Ep + 255) / 256;
    int NBS  = (Ep + 1023) / 1024;
    int NBA  = (N + 15) / 16;

    hist_uv_k<<<NBH + 2, 256, 0, stream>>>(ei_dst, deg, pos, E, Ep, NBH,
                                           W1, as1, ad1, UV4, Wth, Wtl);
    scanA_att_k<<<NBLK + NBA, 1024, 0, stream>>>(deg, rloc, bsum, N, NBLK,
                                                 x, UV4, a_src1, a_dst1);
    scat_fix_k<<<NBLK + NBS, 1024, 0, stream>>>(ei_src, ei_dst, rloc, bsum, pos,
                                                rowptr, csr_src, csr_eid,
                                                E, Ep, N, NBLK);

    // layer 1: aggregate x into split-f16 G, then LDS-fragment MFMA GEMM
    agg1x<<<(N + 3) / 4, 256, 0, stream>>>(rowptr, csr_src, a_src1, a_dst1, x,
                                           Gh, Gl, N);
    gemm1_mfma<<<dim3((N + 63) / 64, 2), 256, 0, stream>>>(Gh, Gl, Wth, Wtl, z1, N);

    // layer 2 (vector GEMM, relu+bias staged, att epilogue)
    int mt1 = (N + 127) / 128;
    gemm_tiled<F1, 128, 64, 4, 8, F1, F2, F2, true, true, false>
        <<<dim3(mt1, 1), 256, 0, stream>>>(
        z1, b1, W2, xh2, as2, ad2, a_src2, a_dst2, N);
    agg2_csr<<<(N + 3) / 4, 256, 0, stream>>>(rowptr, csr_src, a_src2, a_dst2, xh2, b2, out2b, N);

    // decode via CSR
    decode_csr<<<(N + 3) / 4, 256, 0, stream>>>(rowptr, csr_src, csr_eid, out2b,
                                                (float*)d_out, N);
}

// Round 17
// 326.890 us; speedup vs baseline: 1.1743x; 1.0182x over previous
//
#include <hip/hip_runtime.h>
#include <math.h>

#define IN_F 128
#define F1 256   // H1*C1
#define H1 2
#define F2 64
#define NEG 0.2f

typedef _Float16 f16x8 __attribute__((ext_vector_type(8)));
typedef _Float16 f16x4 __attribute__((ext_vector_type(4)));
typedef float f32x4 __attribute__((ext_vector_type(4)));

// ------- layer-1 GEMM via split-f16 MFMA, LDS-fragment B ---------------------
// One head per block (blockIdx.y). B pre-swizzled into MFMA-frag layout in
// LDS (lane-linear 16B ds_reads, conflict-free). 8 independent ct chains.
// Epilogue fuses relu(z+b1) and emits split-f16 zh/zl (gemm2's A operand).
__global__ __launch_bounds__(256) void gemm1_mfma(
    const _Float16* __restrict__ Gh, const _Float16* __restrict__ Gl,
    const _Float16* __restrict__ Wth, const _Float16* __restrict__ Wtl,
    const float* __restrict__ b1,
    _Float16* __restrict__ zh, _Float16* __restrict__ zl, int N)
{
    __shared__ _Float16 BhF[32 * 64 * 8];   // 32 KB: [ct*4+ks][lane][8]
    __shared__ _Float16 BlF[32 * 64 * 8];   // 32 KB
    int t = threadIdx.x;
    int h = blockIdx.y;
    const _Float16* wsh = Wth + (long)h * 128 * IN_F;
    const _Float16* wsl = Wtl + (long)h * 128 * IN_F;
    #pragma unroll
    for (int p = 0; p < 8; ++p) {
        int fs = p * 256 + t;
        int lane = fs & 63;
        int slot = fs >> 6;              // ct*4+ks
        int ct = slot >> 2, ks = slot & 3;
        int col = ct * 16 + (lane & 15);
        int koff = ks * 32 + (lane >> 4) * 8;
        *(f16x8*)&BhF[fs * 8] = *(const f16x8*)&wsh[(long)col * IN_F + koff];
        *(f16x8*)&BlF[fs * 8] = *(const f16x8*)&wsl[(long)col * IN_F + koff];
    }
    __syncthreads();

    int wave = t >> 6, lane = t & 63;
    int quad = lane >> 4, l4 = lane & 15;
    int rt = blockIdx.x * 4 + wave;      // row-tile of 16 (N%16==0)
    if (rt * 16 >= N) return;
    long mrow = (long)rt * 16 + l4;
    const _Float16* gh = Gh + mrow * F1 + h * 128 + quad * 8;
    const _Float16* gl = Gl + mrow * F1 + h * 128 + quad * 8;
    f16x8 ah[4], al[4];
    #pragma unroll
    for (int ks = 0; ks < 4; ++ks) {
        ah[ks] = *(const f16x8*)(gh + ks * 32);
        al[ks] = *(const f16x8*)(gl + ks * 32);
    }
    f32x4 acc[8];
    #pragma unroll
    for (int ct = 0; ct < 8; ++ct) acc[ct] = (f32x4){0.f, 0.f, 0.f, 0.f};
    #pragma unroll
    for (int ks = 0; ks < 4; ++ks) {
        #pragma unroll
        for (int ct = 0; ct < 8; ++ct) {
            f16x8 bh = *(const f16x8*)&BhF[((ct * 4 + ks) * 64 + lane) * 8];
            f16x8 bl = *(const f16x8*)&BlF[((ct * 4 + ks) * 64 + lane) * 8];
            acc[ct] = __builtin_amdgcn_mfma_f32_16x16x32_f16(ah[ks], bh, acc[ct], 0, 0, 0);
            acc[ct] = __builtin_amdgcn_mfma_f32_16x16x32_f16(al[ks], bh, acc[ct], 0, 0, 0);
            acc[ct] = __builtin_amdgcn_mfma_f32_16x16x32_f16(ah[ks], bl, acc[ct], 0, 0, 0);
        }
    }
    int rbase = rt * 16 + quad * 4;
    #pragma unroll
    for (int ct = 0; ct < 8; ++ct) {
        int col = h * 128 + ct * 16 + l4;
        float b1c = b1[col];
        #pragma unroll
        for (int i = 0; i < 4; ++i) {
            float v = fmaxf(acc[ct][i] + b1c, 0.f);   // relu(z+b1) fused
            _Float16 hi = (_Float16)v;
            long idx = (long)(rbase + i) * F1 + col;
            zh[idx] = hi;
            zl[idx] = (_Float16)(v - (float)hi);
        }
    }
}

// ------- layer-2 GEMM via split-f16 MFMA: xh2 = z @ W2, + att2 epilogue ------
// Same structure as gemm1_mfma: W2 hi/lo fragments in LDS (64 KB), K=256
// (8 k-steps), 4 col-tiles, 96 MFMAs/wave. att2 row dots computed from
// C-layout accumulators via convergent 16-lane shuffle reduction.
__global__ __launch_bounds__(256) void gemm2_mfma(
    const _Float16* __restrict__ zh, const _Float16* __restrict__ zl,
    const _Float16* __restrict__ W2th, const _Float16* __restrict__ W2tl,
    const float* __restrict__ as2, const float* __restrict__ ad2,
    float* __restrict__ xh2, float* __restrict__ a_src, float* __restrict__ a_dst,
    int N)
{
    __shared__ _Float16 BhF[32 * 64 * 8];   // 32 KB: [ct*8+ks][lane][8]
    __shared__ _Float16 BlF[32 * 64 * 8];
    int t = threadIdx.x;
    #pragma unroll
    for (int p = 0; p < 8; ++p) {
        int fs = p * 256 + t;
        int lane = fs & 63;
        int slot = fs >> 6;              // ct*8+ks (ct<4, ks<8)
        int ct = slot >> 3, ks = slot & 7;
        int col = ct * 16 + (lane & 15);
        int koff = ks * 32 + (lane >> 4) * 8;
        *(f16x8*)&BhF[fs * 8] = *(const f16x8*)&W2th[(long)col * F1 + koff];
        *(f16x8*)&BlF[fs * 8] = *(const f16x8*)&W2tl[(long)col * F1 + koff];
    }
    __syncthreads();

    int wave = t >> 6, lane = t & 63;
    int quad = lane >> 4, l4 = lane & 15;
    int rt = blockIdx.x * 4 + wave;
    if (rt * 16 >= N) return;
    long mrow = (long)rt * 16 + l4;
    const _Float16* ap = zh + mrow * F1 + quad * 8;
    const _Float16* alp = zl + mrow * F1 + quad * 8;
    f16x8 ah[8], al[8];
    #pragma unroll
    for (int ks = 0; ks < 8; ++ks) {
        ah[ks] = *(const f16x8*)(ap + ks * 32);
        al[ks] = *(const f16x8*)(alp + ks * 32);
    }
    f32x4 acc[4];
    #pragma unroll
    for (int ct = 0; ct < 4; ++ct) acc[ct] = (f32x4){0.f, 0.f, 0.f, 0.f};
    #pragma unroll
    for (int ks = 0; ks < 8; ++ks) {
        #pragma unroll
        for (int ct = 0; ct < 4; ++ct) {
            f16x8 bh = *(const f16x8*)&BhF[((ct * 8 + ks) * 64 + lane) * 8];
            f16x8 bl = *(const f16x8*)&BlF[((ct * 8 + ks) * 64 + lane) * 8];
            acc[ct] = __builtin_amdgcn_mfma_f32_16x16x32_f16(ah[ks], bh, acc[ct], 0, 0, 0);
            acc[ct] = __builtin_amdgcn_mfma_f32_16x16x32_f16(al[ks], bh, acc[ct], 0, 0, 0);
            acc[ct] = __builtin_amdgcn_mfma_f32_16x16x32_f16(ah[ks], bl, acc[ct], 0, 0, 0);
        }
    }
    int rbase = rt * 16 + quad * 4;
    float ps[4] = {0, 0, 0, 0}, pd[4] = {0, 0, 0, 0};
    #pragma unroll
    for (int ct = 0; ct < 4; ++ct) {
        int col = ct * 16 + l4;
        float asv = as2[col], adv = ad2[col];
        #pragma unroll
        for (int i = 0; i < 4; ++i) {
            xh2[(long)(rbase + i) * F2 + col] = acc[ct][i];
            ps[i] = fmaf(acc[ct][i], asv, ps[i]);
            pd[i] = fmaf(acc[ct][i], adv, pd[i]);
        }
    }
    #pragma unroll
    for (int o = 1; o < 16; o <<= 1) {
        #pragma unroll
        for (int i = 0; i < 4; ++i) {
            ps[i] += __shfl_xor(ps[i], o);
            pd[i] += __shfl_xor(pd[i], o);
        }
    }
    if (l4 == 0) {
        #pragma unroll
        for (int i = 0; i < 4; ++i) {
            a_src[rbase + i] = ps[i];
            a_dst[rbase + i] = pd[i];
        }
    }
}

// ------- launch 1: histogram + UV precompute + W1/W2 transpose/split ---------
__global__ __launch_bounds__(256) void hist_uv_k(
    const int* __restrict__ ei_d, int* __restrict__ deg, int* __restrict__ pos,
    int E, int Ep, int NBH,
    const float* __restrict__ W1, const float* __restrict__ as1,
    const float* __restrict__ ad1, float* __restrict__ UV4,
    _Float16* __restrict__ Wth, _Float16* __restrict__ Wtl,
    const float* __restrict__ W2,
    _Float16* __restrict__ W2th, _Float16* __restrict__ W2tl)
{
    if ((int)blockIdx.x < NBH) {
        int i = blockIdx.x * 256 + threadIdx.x;
        if (i >= Ep) return;
        int d = (i < E) ? ei_d[i] : (i - E);
        pos[i] = atomicAdd(&deg[d], 1);
    } else if ((int)blockIdx.x == NBH) {
        int t = threadIdx.x;
        int k = t >> 1, h = t & 1;
        const float* wrow = W1 + (long)k * F1 + h * 128;
        const float* sa = as1 + h * 128;
        const float* da = ad1 + h * 128;
        float u = 0.f, v = 0.f;
        for (int c = 0; c < 128; ++c) {
            float w = wrow[c];
            u = fmaf(w, sa[c], u);
            v = fmaf(w, da[c], v);
        }
        UV4[k * 4 + h] = u;
        UV4[k * 4 + 2 + h] = v;
    } else if ((int)blockIdx.x == NBH + 1) {
        // W1t[n][k] split into f16 hi/lo
        int n = threadIdx.x;
        for (int k = 0; k < IN_F; ++k) {
            float w = W1[(long)k * F1 + n];
            _Float16 hh = (_Float16)w;
            Wth[(long)n * IN_F + k] = hh;
            Wtl[(long)n * IN_F + k] = (_Float16)(w - (float)hh);
        }
    } else {
        // W2t[n][k] split into f16 hi/lo (n<64, k<256)
        int n = threadIdx.x;
        if (n < F2) {
            for (int k = 0; k < F1; ++k) {
                float w = W2[(long)k * F2 + n];
                _Float16 hh = (_Float16)w;
                W2th[(long)n * F1 + k] = hh;
                W2tl[(long)n * F1 + k] = (_Float16)(w - (float)hh);
            }
        }
    }
}

// ------- launch 2: per-block local scan -> rloc + att1v ----------------------
__global__ __launch_bounds__(1024) void scanA_att_k(
    const int* __restrict__ deg, int* __restrict__ rloc, int* __restrict__ bsum,
    int N, int NBLK,
    const float* __restrict__ x, const float* __restrict__ UV4,
    float* __restrict__ a_src, float* __restrict__ a_dst)
{
    if ((int)blockIdx.x < NBLK) {
        __shared__ int wsum[16];
        int t = threadIdx.x, lane = t & 63, w = t >> 6;
        int i = blockIdx.x * 1024 + t;
        int v = (i < N) ? deg[i] : 0;
        int incl = v;
        #pragma unroll
        for (int o = 1; o < 64; o <<= 1) {
            int nb = __shfl_up(incl, o);
            if (lane >= o) incl += nb;
        }
        if (lane == 63) wsum[w] = incl;
        __syncthreads();
        if (w == 0 && lane < 16) {
            int s = wsum[lane];
            #pragma unroll
            for (int o = 1; o < 16; o <<= 1) {
                int nb = __shfl_up(s, o);
                if (lane >= o) s += nb;
            }
            wsum[lane] = s;
        }
        __syncthreads();
        int woff = (w == 0) ? 0 : wsum[w - 1];
        if (i < N) rloc[i] = woff + incl - v;
        if (t == 1023) bsum[blockIdx.x] = woff + incl;
    } else {
        int wave = threadIdx.x >> 6, lane = threadIdx.x & 63;
        int n = ((int)blockIdx.x - NBLK) * 16 + wave;
        if (n >= N) return;
        float2 xv = ((const float2*)(x + (long)n * IN_F))[lane];
        float4 u0 = ((const float4*)UV4)[2 * lane];
        float4 u1 = ((const float4*)UV4)[2 * lane + 1];
        float p0 = xv.x * u0.x + xv.y * u1.x;
        float p1 = xv.x * u0.y + xv.y * u1.y;
        float p2 = xv.x * u0.z + xv.y * u1.z;
        float p3 = xv.x * u0.w + xv.y * u1.w;
        #pragma unroll
        for (int o = 32; o > 0; o >>= 1) {
            p0 += __shfl_xor(p0, o); p1 += __shfl_xor(p1, o);
            p2 += __shfl_xor(p2, o); p3 += __shfl_xor(p3, o);
        }
        if (lane == 0) {
            a_src[(long)n * 2 + 0] = p0; a_src[(long)n * 2 + 1] = p1;
            a_dst[(long)n * 2 + 0] = p2; a_dst[(long)n * 2 + 1] = p3;
        }
    }
}

// ------- launch 3 (fused): rowptr fixup + atomic-free scatter ----------------
__global__ __launch_bounds__(1024) void scat_fix_k(
    const int* __restrict__ ei_s, const int* __restrict__ ei_d,
    const int* __restrict__ rloc, const int* __restrict__ bsum,
    const int* __restrict__ pos, int* __restrict__ rowptr,
    int* __restrict__ csr_src, int* __restrict__ csr_eid,
    int E, int Ep, int N, int NBLK)
{
    __shared__ int bexs[64];
    __shared__ int tot_sh;
    int t = threadIdx.x;
    if (t < 64) {
        int v = (t < NBLK) ? bsum[t] : 0;
        int incl = v;
        #pragma unroll
        for (int o = 1; o < 64; o <<= 1) {
            int nb = __shfl_up(incl, o);
            if (t >= o) incl += nb;
        }
        bexs[t] = incl - v;
        if (t == NBLK - 1) tot_sh = incl;
    }
    __syncthreads();
    if ((int)blockIdx.x < NBLK) {
        int i = blockIdx.x * 1024 + t;
        if (i < N) rowptr[i] = rloc[i] + bexs[blockIdx.x];
        if ((int)blockIdx.x == NBLK - 1 && t == 0) rowptr[N] = tot_sh;
    } else {
        int i = ((int)blockIdx.x - NBLK) * 1024 + t;
        if (i >= Ep) return;
        int s = (i < E) ? ei_s[i] : (i - E);
        int d = (i < E) ? ei_d[i] : (i - E);
        int at = rloc[d] + bexs[d >> 10] + pos[i];
        csr_src[at] = s;
        csr_eid[at] = (i < E) ? i : -1;
    }
}

// ------- layer-1 aggregation in INPUT space; emits split-f16 G ---------------
__global__ __launch_bounds__(256) void agg1x(
    const int* __restrict__ rowptr, const int* __restrict__ csr_src,
    const float* __restrict__ a_s, const float* __restrict__ a_d,  // [N,2]
    const float* __restrict__ x, _Float16* __restrict__ Gh,
    _Float16* __restrict__ Gl, int N)
{
    int wave = threadIdx.x >> 6, lane = threadIdx.x & 63;
    int d = blockIdx.x * 4 + wave;
    if (d >= N) return;
    int row = rowptr[d], end = rowptr[d + 1];
    int h = lane >> 5, l5 = lane & 31;
    float adh = a_d[(long)d * 2 + h];
    float a0[4] = {0,0,0,0}, a1[4] = {0,0,0,0};
    float den = 0.f;
    for (int base = row; base < end; base += 32) {
        int cnt = min(32, end - base);
        int sreg = 0; float e = 0.f;
        if (l5 < cnt) {
            sreg = csr_src[base + l5];
            float v = a_s[(long)sreg * 2 + h] + adh;
            v = (v > 0.f) ? v : NEG * v;
            e = expf(v);
            den += e;
        }
        int jmax = (cnt + 1) >> 1;
        for (int j = 0; j < jmax; ++j) {
            int m = 2 * j + h;
            int s = __shfl(sreg, m);
            float w0 = __shfl(e, m);
            float w1 = __shfl(e, 32 | m);
            float4 v = *(const float4*)(x + (long)s * IN_F + l5 * 4);
            a0[0] = fmaf(w0, v.x, a0[0]); a0[1] = fmaf(w0, v.y, a0[1]);
            a0[2] = fmaf(w0, v.z, a0[2]); a0[3] = fmaf(w0, v.w, a0[3]);
            a1[0] = fmaf(w1, v.x, a1[0]); a1[1] = fmaf(w1, v.y, a1[1]);
            a1[2] = fmaf(w1, v.z, a1[2]); a1[3] = fmaf(w1, v.w, a1[3]);
        }
    }
    #pragma unroll
    for (int o = 16; o > 0; o >>= 1) den += __shfl_xor(den, o);
    #pragma unroll
    for (int p = 0; p < 4; ++p) {
        a0[p] += __shfl_xor(a0[p], 32);
        a1[p] += __shfl_xor(a1[p], 32);
    }
    float inv = 1.0f / (den + 1e-16f);
    float* acch = (h == 0) ? a0 : a1;
    f16x4 hi, lo;
    #pragma unroll
    for (int p = 0; p < 4; ++p) {
        float v = acch[p] * inv;
        hi[p] = (_Float16)v;
        lo[p] = (_Float16)(v - (float)hi[p]);
    }
    long base = (long)d * F1 + h * 128 + l5 * 4;
    *(f16x4*)(Gh + base) = hi;
    *(f16x4*)(Gl + base) = lo;
}

// ------- layer-2 aggregation (bias fused into output) ------------------------
__global__ __launch_bounds__(256) void agg2_csr(
    const int* __restrict__ rowptr, const int* __restrict__ csr_src,
    const float* __restrict__ a_s, const float* __restrict__ a_d,  // [N]
    const float* __restrict__ xh2, const float* __restrict__ b2,
    float* __restrict__ out2b, int N)
{
    int wave = threadIdx.x >> 6, lane = threadIdx.x & 63;
    int d = blockIdx.x * 4 + wave;
    if (d >= N) return;
    int row = rowptr[d], end = rowptr[d + 1];
    float adv = a_d[d];
    int g = lane >> 4, q = lane & 15;
    float acc[4] = {0,0,0,0};
    float den = 0.f;
    for (int base = row; base < end; base += 64) {
        int cnt = min(64, end - base);
        float ev = 0.f; int sreg = 0;
        if (lane < cnt) {
            sreg = csr_src[base + lane];
            float v = a_s[sreg] + adv; v = (v > 0.f) ? v : NEG * v;
            ev = expf(v);
            den += ev;
        }
        int jmax = (cnt + 3) >> 2;
        for (int j = 0; j < jmax; ++j) {
            int m = 4 * j + g;
            int s = __shfl(sreg, m);
            float w = __shfl(ev, m);
            float4 v = *(const float4*)(xh2 + (long)s * F2 + q * 4);
            acc[0] = fmaf(w, v.x, acc[0]); acc[1] = fmaf(w, v.y, acc[1]);
            acc[2] = fmaf(w, v.z, acc[2]); acc[3] = fmaf(w, v.w, acc[3]);
        }
    }
    #pragma unroll
    for (int o = 32; o > 0; o >>= 1) den += __shfl_xor(den, o);
    #pragma unroll
    for (int p = 0; p < 4; ++p) {
        acc[p] += __shfl_xor(acc[p], 16);
        acc[p] += __shfl_xor(acc[p], 32);
    }
    if (g == 0) {
        float inv = 1.0f / (den + 1e-16f);
        float4 bb = *(const float4*)&b2[q * 4];
        float4 o4 = {acc[0] * inv + bb.x, acc[1] * inv + bb.y,
                     acc[2] * inv + bb.z, acc[3] * inv + bb.w};
        *(float4*)(out2b + (long)d * F2 + q * 4) = o4;
    }
}

// ------- decode via CSR ------------------------------------------------------
__global__ __launch_bounds__(256) void decode_csr(
    const int* __restrict__ rowptr, const int* __restrict__ csr_src,
    const int* __restrict__ csr_eid, const float* __restrict__ z2b,
    float* __restrict__ out, int N)
{
    int wave = threadIdx.x >> 6, lane = threadIdx.x & 63;
    int d = blockIdx.x * 4 + wave;
    if (d >= N) return;
    int row = rowptr[d], end = rowptr[d + 1];
    int g = lane >> 4, q = lane & 15;
    float4 vd = *(const float4*)(z2b + (long)d * F2 + q * 4);
    for (int base = row; base < end; base += 64) {
        int cnt = min(64, end - base);
        int sreg = 0, ereg = -1;
        if (lane < cnt) {
            sreg = csr_src[base + lane];
            ereg = csr_eid[base + lane];
        }
        int jmax = (cnt + 3) >> 2;
        for (int j = 0; j < jmax; ++j) {
            int m = 4 * j + g;
            int s = __shfl(sreg, m);
            int eid = __shfl(ereg, m);
            float4 vs = *(const float4*)(z2b + (long)s * F2 + q * 4);
            float p = vd.x * vs.x + vd.y * vs.y + vd.z * vs.z + vd.w * vs.w;
            #pragma unroll
            for (int o = 1; o < 16; o <<= 1) p += __shfl_xor(p, o);
            if (q == 0 && eid >= 0) out[eid] = p;
        }
    }
}

extern "C" void kernel_launch(void* const* d_in, const int* in_sizes, int n_in,
                              void* d_out, int out_size, void* d_ws, size_t ws_size,
                              hipStream_t stream) {
    const float* x   = (const float*)d_in[0];
    const int*   ei  = (const int*)d_in[1];
    const float* W1  = (const float*)d_in[2];
    const float* as1 = (const float*)d_in[3];
    const float* ad1 = (const float*)d_in[4];
    const float* b1  = (const float*)d_in[5];
    const float* W2  = (const float*)d_in[6];
    const float* as2 = (const float*)d_in[7];
    const float* ad2 = (const float*)d_in[8];
    const float* b2  = (const float*)d_in[9];

    int N  = in_sizes[0] / IN_F;   // 50000
    int E  = in_sizes[1] / 2;      // 600000
    int Ep = E + N;
    const int* ei_src = ei;
    const int* ei_dst = ei + E;

    float* ws = (float*)d_ws;
    size_t off = 0;
    auto alloc = [&](size_t n) { float* p = ws + off; off += (n + 63) & ~(size_t)63; return p; };

    _Float16* Gh   = (_Float16*)alloc((size_t)N * F1 / 2);
    _Float16* Gl   = (_Float16*)alloc((size_t)N * F1 / 2);
    _Float16* zh   = (_Float16*)alloc((size_t)N * F1 / 2);
    _Float16* zl   = (_Float16*)alloc((size_t)N * F1 / 2);
    _Float16* Wth  = (_Float16*)alloc(IN_F * F1 / 2);
    _Float16* Wtl  = (_Float16*)alloc(IN_F * F1 / 2);
    _Float16* W2th = (_Float16*)alloc(F1 * F2 / 2);
    _Float16* W2tl = (_Float16*)alloc(F1 * F2 / 2);
    float* xh2    = alloc((size_t)N * F2);
    float* out2b  = alloc((size_t)N * F2);
    float* a_src1 = alloc((size_t)N * H1);
    float* a_dst1 = alloc((size_t)N * H1);
    float* a_src2 = alloc(N);
    float* a_dst2 = alloc(N);
    float* UV4    = alloc(IN_F * 4);
    int* rowptr   = (int*)alloc(N + 64);
    int* rloc     = (int*)alloc(N + 64);
    int* csr_src  = (int*)alloc(Ep);
    int* csr_eid  = (int*)alloc(Ep);
    int* pos      = (int*)alloc(Ep);
    int* bsum     = (int*)alloc(64);
    int* deg      = (int*)alloc(N);
    hipMemsetAsync(deg, 0, (size_t)N * sizeof(int), stream);

    int NBLK = (N + 1023) / 1024;       // 49
    int NBH  = (Ep + 255) / 256;
    int NBS  = (Ep + 1023) / 1024;
    int NBA  = (N + 15) / 16;

    hist_uv_k<<<NBH + 3, 256, 0, stream>>>(ei_dst, deg, pos, E, Ep, NBH,
                                           W1, as1, ad1, UV4, Wth, Wtl,
                                           W2, W2th, W2tl);
    scanA_att_k<<<NBLK + NBA, 1024, 0, stream>>>(deg, rloc, bsum, N, NBLK,
                                                 x, UV4, a_src1, a_dst1);
    scat_fix_k<<<NBLK + NBS, 1024, 0, stream>>>(ei_src, ei_dst, rloc, bsum, pos,
                                                rowptr, csr_src, csr_eid,
                                                E, Ep, N, NBLK);

    // layer 1: aggregate x into split-f16 G, LDS-fragment MFMA GEMM,
    // epilogue emits relu(z+b1) as split-f16
    agg1x<<<(N + 3) / 4, 256, 0, stream>>>(rowptr, csr_src, a_src1, a_dst1, x,
                                           Gh, Gl, N);
    gemm1_mfma<<<dim3((N + 63) / 64, 2), 256, 0, stream>>>(Gh, Gl, Wth, Wtl,
                                                           b1, zh, zl, N);

    // layer 2: MFMA GEMM with fused att2 epilogue
    gemm2_mfma<<<(N + 63) / 64, 256, 0, stream>>>(zh, zl, W2th, W2tl,
                                                  as2, ad2, xh2, a_src2, a_dst2, N);
    agg2_csr<<<(N + 3) / 4, 256, 0, stream>>>(rowptr, csr_src, a_src2, a_dst2, xh2, b2, out2b, N);

    // decode via CSR
    decode_csr<<<(N + 3) / 4, 256, 0, stream>>>(rowptr, csr_src, csr_eid, out2b,
                                                (float*)d_out, N);
}

// Round 18
// 315.677 us; speedup vs baseline: 1.2161x; 1.0355x over previous
//
#include <hip/hip_runtime.h>
#include <math.h>

#define IN_F 128
#define F1 256   // H1*C1
#define H1 2
#define F2 64
#define NEG 0.2f

typedef _Float16 f16x8 __attribute__((ext_vector_type(8)));
typedef _Float16 f16x4 __attribute__((ext_vector_type(4)));
typedef float f32x4 __attribute__((ext_vector_type(4)));

// ------- layer-1 GEMM via split-f16 MFMA, LDS-fragment B ---------------------
__global__ __launch_bounds__(256) void gemm1_mfma(
    const _Float16* __restrict__ Gh, const _Float16* __restrict__ Gl,
    const _Float16* __restrict__ Wth, const _Float16* __restrict__ Wtl,
    const float* __restrict__ b1,
    _Float16* __restrict__ zh, _Float16* __restrict__ zl, int N)
{
    __shared__ _Float16 BhF[32 * 64 * 8];
    __shared__ _Float16 BlF[32 * 64 * 8];
    int t = threadIdx.x;
    int h = blockIdx.y;
    const _Float16* wsh = Wth + (long)h * 128 * IN_F;
    const _Float16* wsl = Wtl + (long)h * 128 * IN_F;
    #pragma unroll
    for (int p = 0; p < 8; ++p) {
        int fs = p * 256 + t;
        int lane = fs & 63;
        int slot = fs >> 6;
        int ct = slot >> 2, ks = slot & 3;
        int col = ct * 16 + (lane & 15);
        int koff = ks * 32 + (lane >> 4) * 8;
        *(f16x8*)&BhF[fs * 8] = *(const f16x8*)&wsh[(long)col * IN_F + koff];
        *(f16x8*)&BlF[fs * 8] = *(const f16x8*)&wsl[(long)col * IN_F + koff];
    }
    __syncthreads();

    int wave = t >> 6, lane = t & 63;
    int quad = lane >> 4, l4 = lane & 15;
    int rt = blockIdx.x * 4 + wave;
    if (rt * 16 >= N) return;
    long mrow = (long)rt * 16 + l4;
    const _Float16* gh = Gh + mrow * F1 + h * 128 + quad * 8;
    const _Float16* gl = Gl + mrow * F1 + h * 128 + quad * 8;
    f16x8 ah[4], al[4];
    #pragma unroll
    for (int ks = 0; ks < 4; ++ks) {
        ah[ks] = *(const f16x8*)(gh + ks * 32);
        al[ks] = *(const f16x8*)(gl + ks * 32);
    }
    f32x4 acc[8];
    #pragma unroll
    for (int ct = 0; ct < 8; ++ct) acc[ct] = (f32x4){0.f, 0.f, 0.f, 0.f};
    #pragma unroll
    for (int ks = 0; ks < 4; ++ks) {
        #pragma unroll
        for (int ct = 0; ct < 8; ++ct) {
            f16x8 bh = *(const f16x8*)&BhF[((ct * 4 + ks) * 64 + lane) * 8];
            f16x8 bl = *(const f16x8*)&BlF[((ct * 4 + ks) * 64 + lane) * 8];
            acc[ct] = __builtin_amdgcn_mfma_f32_16x16x32_f16(ah[ks], bh, acc[ct], 0, 0, 0);
            acc[ct] = __builtin_amdgcn_mfma_f32_16x16x32_f16(al[ks], bh, acc[ct], 0, 0, 0);
            acc[ct] = __builtin_amdgcn_mfma_f32_16x16x32_f16(ah[ks], bl, acc[ct], 0, 0, 0);
        }
    }
    int rbase = rt * 16 + quad * 4;
    #pragma unroll
    for (int ct = 0; ct < 8; ++ct) {
        int col = h * 128 + ct * 16 + l4;
        float b1c = b1[col];
        #pragma unroll
        for (int i = 0; i < 4; ++i) {
            float v = fmaxf(acc[ct][i] + b1c, 0.f);
            _Float16 hi = (_Float16)v;
            long idx = (long)(rbase + i) * F1 + col;
            zh[idx] = hi;
            zl[idx] = (_Float16)(v - (float)hi);
        }
    }
}

// ------- layer-2 GEMM via split-f16 MFMA + att2 epilogue ---------------------
__global__ __launch_bounds__(256) void gemm2_mfma(
    const _Float16* __restrict__ zh, const _Float16* __restrict__ zl,
    const _Float16* __restrict__ W2th, const _Float16* __restrict__ W2tl,
    const float* __restrict__ as2, const float* __restrict__ ad2,
    float* __restrict__ xh2, float* __restrict__ a_src, float* __restrict__ a_dst,
    int N)
{
    __shared__ _Float16 BhF[32 * 64 * 8];
    __shared__ _Float16 BlF[32 * 64 * 8];
    int t = threadIdx.x;
    #pragma unroll
    for (int p = 0; p < 8; ++p) {
        int fs = p * 256 + t;
        int lane = fs & 63;
        int slot = fs >> 6;
        int ct = slot >> 3, ks = slot & 7;
        int col = ct * 16 + (lane & 15);
        int koff = ks * 32 + (lane >> 4) * 8;
        *(f16x8*)&BhF[fs * 8] = *(const f16x8*)&W2th[(long)col * F1 + koff];
        *(f16x8*)&BlF[fs * 8] = *(const f16x8*)&W2tl[(long)col * F1 + koff];
    }
    __syncthreads();

    int wave = t >> 6, lane = t & 63;
    int quad = lane >> 4, l4 = lane & 15;
    int rt = blockIdx.x * 4 + wave;
    if (rt * 16 >= N) return;
    long mrow = (long)rt * 16 + l4;
    const _Float16* ap = zh + mrow * F1 + quad * 8;
    const _Float16* alp = zl + mrow * F1 + quad * 8;
    f16x8 ah[8], al[8];
    #pragma unroll
    for (int ks = 0; ks < 8; ++ks) {
        ah[ks] = *(const f16x8*)(ap + ks * 32);
        al[ks] = *(const f16x8*)(alp + ks * 32);
    }
    f32x4 acc[4];
    #pragma unroll
    for (int ct = 0; ct < 4; ++ct) acc[ct] = (f32x4){0.f, 0.f, 0.f, 0.f};
    #pragma unroll
    for (int ks = 0; ks < 8; ++ks) {
        #pragma unroll
        for (int ct = 0; ct < 4; ++ct) {
            f16x8 bh = *(const f16x8*)&BhF[((ct * 8 + ks) * 64 + lane) * 8];
            f16x8 bl = *(const f16x8*)&BlF[((ct * 8 + ks) * 64 + lane) * 8];
            acc[ct] = __builtin_amdgcn_mfma_f32_16x16x32_f16(ah[ks], bh, acc[ct], 0, 0, 0);
            acc[ct] = __builtin_amdgcn_mfma_f32_16x16x32_f16(al[ks], bh, acc[ct], 0, 0, 0);
            acc[ct] = __builtin_amdgcn_mfma_f32_16x16x32_f16(ah[ks], bl, acc[ct], 0, 0, 0);
        }
    }
    int rbase = rt * 16 + quad * 4;
    float ps[4] = {0, 0, 0, 0}, pd[4] = {0, 0, 0, 0};
    #pragma unroll
    for (int ct = 0; ct < 4; ++ct) {
        int col = ct * 16 + l4;
        float asv = as2[col], adv = ad2[col];
        #pragma unroll
        for (int i = 0; i < 4; ++i) {
            xh2[(long)(rbase + i) * F2 + col] = acc[ct][i];
            ps[i] = fmaf(acc[ct][i], asv, ps[i]);
            pd[i] = fmaf(acc[ct][i], adv, pd[i]);
        }
    }
    #pragma unroll
    for (int o = 1; o < 16; o <<= 1) {
        #pragma unroll
        for (int i = 0; i < 4; ++i) {
            ps[i] += __shfl_xor(ps[i], o);
            pd[i] += __shfl_xor(pd[i], o);
        }
    }
    if (l4 == 0) {
        #pragma unroll
        for (int i = 0; i < 4; ++i) {
            a_src[rbase + i] = ps[i];
            a_dst[rbase + i] = pd[i];
        }
    }
}

// ------- launch 1: histogram + UV precompute + W1/W2 transpose/split ---------
__global__ __launch_bounds__(256) void hist_uv_k(
    const int* __restrict__ ei_d, int* __restrict__ deg, int* __restrict__ pos,
    int E, int Ep, int NBH,
    const float* __restrict__ W1, const float* __restrict__ as1,
    const float* __restrict__ ad1, float* __restrict__ UV4,
    _Float16* __restrict__ Wth, _Float16* __restrict__ Wtl,
    const float* __restrict__ W2,
    _Float16* __restrict__ W2th, _Float16* __restrict__ W2tl)
{
    if ((int)blockIdx.x < NBH) {
        int i = blockIdx.x * 256 + threadIdx.x;
        if (i >= Ep) return;
        int d = (i < E) ? ei_d[i] : (i - E);
        pos[i] = atomicAdd(&deg[d], 1);
    } else if ((int)blockIdx.x == NBH) {
        int t = threadIdx.x;
        int k = t >> 1, h = t & 1;
        const float* wrow = W1 + (long)k * F1 + h * 128;
        const float* sa = as1 + h * 128;
        const float* da = ad1 + h * 128;
        float u = 0.f, v = 0.f;
        for (int c = 0; c < 128; ++c) {
            float w = wrow[c];
            u = fmaf(w, sa[c], u);
            v = fmaf(w, da[c], v);
        }
        UV4[k * 4 + h] = u;
        UV4[k * 4 + 2 + h] = v;
    } else if ((int)blockIdx.x == NBH + 1) {
        int n = threadIdx.x;
        for (int k = 0; k < IN_F; ++k) {
            float w = W1[(long)k * F1 + n];
            _Float16 hh = (_Float16)w;
            Wth[(long)n * IN_F + k] = hh;
            Wtl[(long)n * IN_F + k] = (_Float16)(w - (float)hh);
        }
    } else {
        int n = threadIdx.x;
        if (n < F2) {
            for (int k = 0; k < F1; ++k) {
                float w = W2[(long)k * F2 + n];
                _Float16 hh = (_Float16)w;
                W2th[(long)n * F1 + k] = hh;
                W2tl[(long)n * F1 + k] = (_Float16)(w - (float)hh);
            }
        }
    }
}

// ------- launch 2: per-block local scan -> rloc + att1v ----------------------
__global__ __launch_bounds__(1024) void scanA_att_k(
    const int* __restrict__ deg, int* __restrict__ rloc, int* __restrict__ bsum,
    int N, int NBLK,
    const float* __restrict__ x, const float* __restrict__ UV4,
    float* __restrict__ a_src, float* __restrict__ a_dst)
{
    if ((int)blockIdx.x < NBLK) {
        __shared__ int wsum[16];
        int t = threadIdx.x, lane = t & 63, w = t >> 6;
        int i = blockIdx.x * 1024 + t;
        int v = (i < N) ? deg[i] : 0;
        int incl = v;
        #pragma unroll
        for (int o = 1; o < 64; o <<= 1) {
            int nb = __shfl_up(incl, o);
            if (lane >= o) incl += nb;
        }
        if (lane == 63) wsum[w] = incl;
        __syncthreads();
        if (w == 0 && lane < 16) {
            int s = wsum[lane];
            #pragma unroll
            for (int o = 1; o < 16; o <<= 1) {
                int nb = __shfl_up(s, o);
                if (lane >= o) s += nb;
            }
            wsum[lane] = s;
        }
        __syncthreads();
        int woff = (w == 0) ? 0 : wsum[w - 1];
        if (i < N) rloc[i] = woff + incl - v;
        if (t == 1023) bsum[blockIdx.x] = woff + incl;
    } else {
        int wave = threadIdx.x >> 6, lane = threadIdx.x & 63;
        int n = ((int)blockIdx.x - NBLK) * 16 + wave;
        if (n >= N) return;
        float2 xv = ((const float2*)(x + (long)n * IN_F))[lane];
        float4 u0 = ((const float4*)UV4)[2 * lane];
        float4 u1 = ((const float4*)UV4)[2 * lane + 1];
        float p0 = xv.x * u0.x + xv.y * u1.x;
        float p1 = xv.x * u0.y + xv.y * u1.y;
        float p2 = xv.x * u0.z + xv.y * u1.z;
        float p3 = xv.x * u0.w + xv.y * u1.w;
        #pragma unroll
        for (int o = 32; o > 0; o >>= 1) {
            p0 += __shfl_xor(p0, o); p1 += __shfl_xor(p1, o);
            p2 += __shfl_xor(p2, o); p3 += __shfl_xor(p3, o);
        }
        if (lane == 0) {
            a_src[(long)n * 2 + 0] = p0; a_src[(long)n * 2 + 1] = p1;
            a_dst[(long)n * 2 + 0] = p2; a_dst[(long)n * 2 + 1] = p3;
        }
    }
}

// ------- launch 3 (fused): rowptr fixup + atomic-free scatter ----------------
__global__ __launch_bounds__(1024) void scat_fix_k(
    const int* __restrict__ ei_s, const int* __restrict__ ei_d,
    const int* __restrict__ rloc, const int* __restrict__ bsum,
    const int* __restrict__ pos, int* __restrict__ rowptr,
    int* __restrict__ csr_src, int* __restrict__ csr_eid,
    int E, int Ep, int N, int NBLK)
{
    __shared__ int bexs[64];
    __shared__ int tot_sh;
    int t = threadIdx.x;
    if (t < 64) {
        int v = (t < NBLK) ? bsum[t] : 0;
        int incl = v;
        #pragma unroll
        for (int o = 1; o < 64; o <<= 1) {
            int nb = __shfl_up(incl, o);
            if (t >= o) incl += nb;
        }
        bexs[t] = incl - v;
        if (t == NBLK - 1) tot_sh = incl;
    }
    __syncthreads();
    if ((int)blockIdx.x < NBLK) {
        int i = blockIdx.x * 1024 + t;
        if (i < N) rowptr[i] = rloc[i] + bexs[blockIdx.x];
        if ((int)blockIdx.x == NBLK - 1 && t == 0) rowptr[N] = tot_sh;
    } else {
        int i = ((int)blockIdx.x - NBLK) * 1024 + t;
        if (i >= Ep) return;
        int s = (i < E) ? ei_s[i] : (i - E);
        int d = (i < E) ? ei_d[i] : (i - E);
        int at = rloc[d] + bexs[d >> 10] + pos[i];
        csr_src[at] = s;
        csr_eid[at] = (i < E) ? i : -1;
    }
}

// ------- layer-1 aggregation: 16-lane groups, 4 edges in flight --------------
// Lane q=lane&15 owns channels {q*4..+3} and {64+q*4..+3} (2 float4 / edge).
// Chunk of 32 edges: lanes 0-31 exp head0, 32-63 exp head1. Group g=lane>>4
// handles edge 4j+g. Cross-group combine (xor 16/32) once at the end.
__global__ __launch_bounds__(256) void agg1x(
    const int* __restrict__ rowptr, const int* __restrict__ csr_src,
    const float* __restrict__ a_s, const float* __restrict__ a_d,  // [N,2]
    const float* __restrict__ x, _Float16* __restrict__ Gh,
    _Float16* __restrict__ Gl, int N)
{
    int wave = threadIdx.x >> 6, lane = threadIdx.x & 63;
    int d = blockIdx.x * 4 + wave;
    if (d >= N) return;
    int row = rowptr[d], end = rowptr[d + 1];
    int h = lane >> 5, l5 = lane & 31;
    int g = lane >> 4, q = lane & 15;
    float adh = a_d[(long)d * 2 + h];
    // acc[seg][head][4]: seg0=ch q*4, seg1=ch 64+q*4
    float acc[2][2][4];
    #pragma unroll
    for (int s0 = 0; s0 < 2; ++s0)
        #pragma unroll
        for (int h0 = 0; h0 < 2; ++h0)
            #pragma unroll
            for (int p = 0; p < 4; ++p) acc[s0][h0][p] = 0.f;
    float den = 0.f;
    for (int base = row; base < end; base += 32) {
        int cnt = min(32, end - base);
        int sreg = 0; float e = 0.f;
        if (l5 < cnt) {
            sreg = csr_src[base + l5];
            float v = a_s[(long)sreg * 2 + h] + adh;
            v = (v > 0.f) ? v : NEG * v;
            e = expf(v);
            den += e;
        }
        int jmax = (cnt + 3) >> 2;
        for (int j = 0; j < jmax; ++j) {
            int m = 4 * j + g;                  // m <= 31 always
            int s = __shfl(sreg, m);            // overflow m: e=0 -> safe
            float w0 = __shfl(e, m);
            float w1 = __shfl(e, 32 | m);
            const float* xp = x + (long)s * IN_F + q * 4;
            float4 v0 = *(const float4*)(xp);
            float4 v1 = *(const float4*)(xp + 64);
            acc[0][0][0] = fmaf(w0, v0.x, acc[0][0][0]);
            acc[0][0][1] = fmaf(w0, v0.y, acc[0][0][1]);
            acc[0][0][2] = fmaf(w0, v0.z, acc[0][0][2]);
            acc[0][0][3] = fmaf(w0, v0.w, acc[0][0][3]);
            acc[1][0][0] = fmaf(w0, v1.x, acc[1][0][0]);
            acc[1][0][1] = fmaf(w0, v1.y, acc[1][0][1]);
            acc[1][0][2] = fmaf(w0, v1.z, acc[1][0][2]);
            acc[1][0][3] = fmaf(w0, v1.w, acc[1][0][3]);
            acc[0][1][0] = fmaf(w1, v0.x, acc[0][1][0]);
            acc[0][1][1] = fmaf(w1, v0.y, acc[0][1][1]);
            acc[0][1][2] = fmaf(w1, v0.z, acc[0][1][2]);
            acc[0][1][3] = fmaf(w1, v0.w, acc[0][1][3]);
            acc[1][1][0] = fmaf(w1, v1.x, acc[1][1][0]);
            acc[1][1][1] = fmaf(w1, v1.y, acc[1][1][1]);
            acc[1][1][2] = fmaf(w1, v1.z, acc[1][1][2]);
            acc[1][1][3] = fmaf(w1, v1.w, acc[1][1][3]);
        }
    }
    // den: reduce within each 32-lane half, then exchange across halves
    #pragma unroll
    for (int o = 16; o > 0; o >>= 1) den += __shfl_xor(den, o);
    float den_o = __shfl_xor(den, 32);
    float den0 = (h == 0) ? den : den_o;
    float den1 = (h == 0) ? den_o : den;
    // cross-group combine
    #pragma unroll
    for (int s0 = 0; s0 < 2; ++s0)
        #pragma unroll
        for (int h0 = 0; h0 < 2; ++h0)
            #pragma unroll
            for (int p = 0; p < 4; ++p) {
                float v = acc[s0][h0][p];
                v += __shfl_xor(v, 16);
                v += __shfl_xor(v, 32);
                acc[s0][h0][p] = v;
            }
    if (g == 0) {
        float inv0 = 1.0f / (den0 + 1e-16f);
        float inv1 = 1.0f / (den1 + 1e-16f);
        #pragma unroll
        for (int h0 = 0; h0 < 2; ++h0) {
            float inv = (h0 == 0) ? inv0 : inv1;
            #pragma unroll
            for (int s0 = 0; s0 < 2; ++s0) {
                f16x4 hi, lo;
                #pragma unroll
                for (int p = 0; p < 4; ++p) {
                    float v = acc[s0][h0][p] * inv;
                    hi[p] = (_Float16)v;
                    lo[p] = (_Float16)(v - (float)hi[p]);
                }
                long base = (long)d * F1 + h0 * 128 + s0 * 64 + q * 4;
                *(f16x4*)(Gh + base) = hi;
                *(f16x4*)(Gl + base) = lo;
            }
        }
    }
}

// ------- layer-2 aggregation: 8-lane groups, 8 edges in flight ---------------
__global__ __launch_bounds__(256) void agg2_csr(
    const int* __restrict__ rowptr, const int* __restrict__ csr_src,
    const float* __restrict__ a_s, const float* __restrict__ a_d,  // [N]
    const float* __restrict__ xh2, const float* __restrict__ b2,
    float* __restrict__ out2b, int N)
{
    int wave = threadIdx.x >> 6, lane = threadIdx.x & 63;
    int d = blockIdx.x * 4 + wave;
    if (d >= N) return;
    int row = rowptr[d], end = rowptr[d + 1];
    float adv = a_d[d];
    int g = lane >> 3, q = lane & 7;
    float acc[2][4] = {{0,0,0,0},{0,0,0,0}};
    float den = 0.f;
    for (int base = row; base < end; base += 64) {
        int cnt = min(64, end - base);
        float ev = 0.f; int sreg = 0;
        if (lane < cnt) {
            sreg = csr_src[base + lane];
            float v = a_s[sreg] + adv; v = (v > 0.f) ? v : NEG * v;
            ev = expf(v);
            den += ev;
        }
        int jmax = (cnt + 7) >> 3;
        for (int j = 0; j < jmax; ++j) {
            int m = 8 * j + g;                  // m <= 63 always
            int s = __shfl(sreg, m);            // overflow m: w=0 -> safe
            float w = __shfl(ev, m);
            const float* xp = xh2 + (long)s * F2 + q * 4;
            float4 v0 = *(const float4*)(xp);
            float4 v1 = *(const float4*)(xp + 32);
            acc[0][0] = fmaf(w, v0.x, acc[0][0]); acc[0][1] = fmaf(w, v0.y, acc[0][1]);
            acc[0][2] = fmaf(w, v0.z, acc[0][2]); acc[0][3] = fmaf(w, v0.w, acc[0][3]);
            acc[1][0] = fmaf(w, v1.x, acc[1][0]); acc[1][1] = fmaf(w, v1.y, acc[1][1]);
            acc[1][2] = fmaf(w, v1.z, acc[1][2]); acc[1][3] = fmaf(w, v1.w, acc[1][3]);
        }
    }
    #pragma unroll
    for (int o = 32; o > 0; o >>= 1) den += __shfl_xor(den, o);
    #pragma unroll
    for (int s0 = 0; s0 < 2; ++s0)
        #pragma unroll
        for (int p = 0; p < 4; ++p) {
            float v = acc[s0][p];
            v += __shfl_xor(v, 8);
            v += __shfl_xor(v, 16);
            v += __shfl_xor(v, 32);
            acc[s0][p] = v;
        }
    if (g == 0) {
        float inv = 1.0f / (den + 1e-16f);
        #pragma unroll
        for (int s0 = 0; s0 < 2; ++s0) {
            const float* bb = b2 + s0 * 32 + q * 4;
            float4 o4 = {acc[s0][0] * inv + bb[0], acc[s0][1] * inv + bb[1],
                         acc[s0][2] * inv + bb[2], acc[s0][3] * inv + bb[3]};
            *(float4*)(out2b + (long)d * F2 + s0 * 32 + q * 4) = o4;
        }
    }
}

// ------- decode via CSR: 8-lane groups, 8 edges in flight --------------------
__global__ __launch_bounds__(256) void decode_csr(
    const int* __restrict__ rowptr, const int* __restrict__ csr_src,
    const int* __restrict__ csr_eid, const float* __restrict__ z2b,
    float* __restrict__ out, int N)
{
    int wave = threadIdx.x >> 6, lane = threadIdx.x & 63;
    int d = blockIdx.x * 4 + wave;
    if (d >= N) return;
    int row = rowptr[d], end = rowptr[d + 1];
    int g = lane >> 3, q = lane & 7;
    const float* zd = z2b + (long)d * F2 + q * 4;
    float4 vd0 = *(const float4*)(zd);
    float4 vd1 = *(const float4*)(zd + 32);
    for (int base = row; base < end; base += 64) {
        int cnt = min(64, end - base);
        int sreg = 0, ereg = -1;
        if (lane < cnt) {
            sreg = csr_src[base + lane];
            ereg = csr_eid[base + lane];
        }
        int jmax = (cnt + 7) >> 3;
        for (int j = 0; j < jmax; ++j) {
            int m = 8 * j + g;
            int s = __shfl(sreg, m);
            int eid = __shfl(ereg, m);          // overflow m: ereg=-1 -> skip
            const float* zs = z2b + (long)s * F2 + q * 4;
            float4 v0 = *(const float4*)(zs);
            float4 v1 = *(const float4*)(zs + 32);
            float p = vd0.x * v0.x + vd0.y * v0.y + vd0.z * v0.z + vd0.w * v0.w
                    + vd1.x * v1.x + vd1.y * v1.y + vd1.z * v1.z + vd1.w * v1.w;
            p += __shfl_xor(p, 1);
            p += __shfl_xor(p, 2);
            p += __shfl_xor(p, 4);
            if (q == 0 && eid >= 0) out[eid] = p;
        }
    }
}

extern "C" void kernel_launch(void* const* d_in, const int* in_sizes, int n_in,
                              void* d_out, int out_size, void* d_ws, size_t ws_size,
                              hipStream_t stream) {
    const float* x   = (const float*)d_in[0];
    const int*   ei  = (const int*)d_in[1];
    const float* W1  = (const float*)d_in[2];
    const float* as1 = (const float*)d_in[3];
    const float* ad1 = (const float*)d_in[4];
    const float* b1  = (const float*)d_in[5];
    const float* W2  = (const float*)d_in[6];
    const float* as2 = (const float*)d_in[7];
    const float* ad2 = (const float*)d_in[8];
    const float* b2  = (const float*)d_in[9];

    int N  = in_sizes[0] / IN_F;   // 50000
    int E  = in_sizes[1] / 2;      // 600000
    int Ep = E + N;
    const int* ei_src = ei;
    const int* ei_dst = ei + E;

    float* ws = (float*)d_ws;
    size_t off = 0;
    auto alloc = [&](size_t n) { float* p = ws + off; off += (n + 63) & ~(size_t)63; return p; };

    _Float16* Gh   = (_Float16*)alloc((size_t)N * F1 / 2);
    _Float16* Gl   = (_Float16*)alloc((size_t)N * F1 / 2);
    _Float16* zh   = (_Float16*)alloc((size_t)N * F1 / 2);
    _Float16* zl   = (_Float16*)alloc((size_t)N * F1 / 2);
    _Float16* Wth  = (_Float16*)alloc(IN_F * F1 / 2);
    _Float16* Wtl  = (_Float16*)alloc(IN_F * F1 / 2);
    _Float16* W2th = (_Float16*)alloc(F1 * F2 / 2);
    _Float16* W2tl = (_Float16*)alloc(F1 * F2 / 2);
    float* xh2    = alloc((size_t)N * F2);
    float* out2b  = alloc((size_t)N * F2);
    float* a_src1 = alloc((size_t)N * H1);
    float* a_dst1 = alloc((size_t)N * H1);
    float* a_src2 = alloc(N);
    float* a_dst2 = alloc(N);
    float* UV4    = alloc(IN_F * 4);
    int* rowptr   = (int*)alloc(N + 64);
    int* rloc     = (int*)alloc(N + 64);
    int* csr_src  = (int*)alloc(Ep);
    int* csr_eid  = (int*)alloc(Ep);
    int* pos      = (int*)alloc(Ep);
    int* bsum     = (int*)alloc(64);
    int* deg      = (int*)alloc(N);
    hipMemsetAsync(deg, 0, (size_t)N * sizeof(int), stream);

    int NBLK = (N + 1023) / 1024;       // 49
    int NBH  = (Ep + 255) / 256;
    int NBS  = (Ep + 1023) / 1024;
    int NBA  = (N + 15) / 16;

    hist_uv_k<<<NBH + 3, 256, 0, stream>>>(ei_dst, deg, pos, E, Ep, NBH,
                                           W1, as1, ad1, UV4, Wth, Wtl,
                                           W2, W2th, W2tl);
    scanA_att_k<<<NBLK + NBA, 1024, 0, stream>>>(deg, rloc, bsum, N, NBLK,
                                                 x, UV4, a_src1, a_dst1);
    scat_fix_k<<<NBLK + NBS, 1024, 0, stream>>>(ei_src, ei_dst, rloc, bsum, pos,
                                                rowptr, csr_src, csr_eid,
                                                E, Ep, N, NBLK);

    // layer 1
    agg1x<<<(N + 3) / 4, 256, 0, stream>>>(rowptr, csr_src, a_src1, a_dst1, x,
                                           Gh, Gl, N);
    gemm1_mfma<<<dim3((N + 63) / 64, 2), 256, 0, stream>>>(Gh, Gl, Wth, Wtl,
                                                           b1, zh, zl, N);

    // layer 2
    gemm2_mfma<<<(N + 63) / 64, 256, 0, stream>>>(zh, zl, W2th, W2tl,
                                                  as2, ad2, xh2, a_src2, a_dst2, N);
    agg2_csr<<<(N + 3) / 4, 256, 0, stream>>>(rowptr, csr_src, a_src2, a_dst2, xh2, b2, out2b, N);

    // decode
    decode_csr<<<(N + 3) / 4, 256, 0, stream>>>(rowptr, csr_src, csr_eid, out2b,
                                                (float*)d_out, N);
}